// Round 1
// baseline (2043.254 us; speedup 1.0000x reference)
//
#include <hip/hip_runtime.h>
#include <math.h>

#define B_   2
#define S_   1024
#define HID_ 2048
#define HQ_  32
#define HKV_ 8
#define HD_  64
// n_rep = HQ_/HKV_ = 4

// ---------------------------------------------------------------------------
// C = A(MxK) @ B(KxN), all fp32 row-major. BM=BN=64, BK=16, 256 threads,
// each thread computes a 4x4 micro-tile. All dims are multiples of 64/16 here
// (M=2048, N in {2048,512}, K=2048) so no bounds checks.
// ---------------------------------------------------------------------------
__global__ __launch_bounds__(256) void gemm_f32(const float* __restrict__ A,
                                                const float* __restrict__ Bm,
                                                float* __restrict__ C,
                                                int M, int N, int K) {
    __shared__ __align__(16) float As[16][64];   // [k][m] (transposed stage)
    __shared__ __align__(16) float Bs[16][64];   // [k][n]

    const int tid = threadIdx.x;
    const int bm  = blockIdx.y * 64;
    const int bn  = blockIdx.x * 64;
    const int tm  = (tid >> 4) * 4;     // 0..60
    const int tn  = (tid & 15) * 4;     // 0..60

    // A stage: 64 rows x 16 cols = 256 float4
    const int a_r = tid >> 2;           // 0..63
    const int a_c = (tid & 3) * 4;      // 0,4,8,12
    // B stage: 16 rows x 64 cols = 256 float4
    const int b_r = tid >> 4;           // 0..15
    const int b_c = (tid & 15) * 4;     // 0..60

    float acc[4][4] = {};

    for (int k0 = 0; k0 < K; k0 += 16) {
        float4 av = *(const float4*)&A[(size_t)(bm + a_r) * K + k0 + a_c];
        float4 bv = *(const float4*)&Bm[(size_t)(k0 + b_r) * N + bn + b_c];
        __syncthreads();  // previous iteration's compute done before overwrite
        As[a_c + 0][a_r] = av.x;
        As[a_c + 1][a_r] = av.y;
        As[a_c + 2][a_r] = av.z;
        As[a_c + 3][a_r] = av.w;
        *(float4*)&Bs[b_r][b_c] = bv;
        __syncthreads();
#pragma unroll
        for (int k = 0; k < 16; ++k) {
            float4 a = *(const float4*)&As[k][tm];
            float4 b = *(const float4*)&Bs[k][tn];
            float ar[4] = {a.x, a.y, a.z, a.w};
            float br[4] = {b.x, b.y, b.z, b.w};
#pragma unroll
            for (int i = 0; i < 4; ++i)
#pragma unroll
                for (int j = 0; j < 4; ++j)
                    acc[i][j] = fmaf(ar[i], br[j], acc[i][j]);
        }
    }

#pragma unroll
    for (int i = 0; i < 4; ++i) {
        float4 o = {acc[i][0], acc[i][1], acc[i][2], acc[i][3]};
        *(float4*)&C[(size_t)(bm + tm + i) * N + bn + tn] = o;
    }
}

// ---------------------------------------------------------------------------
// RoPE in-place on Q (B,S,HQ,HD) and K (B,S,HKV,HD).
// new[d]    = x[d]*cos[d]    - x[d+32]*sin[d]       (d < 32)
// new[d+32] = x[d+32]*cos[d+32] + x[d]*sin[d+32]
// ---------------------------------------------------------------------------
__global__ __launch_bounds__(256) void rope_kernel(float* __restrict__ Q,
                                                   float* __restrict__ K,
                                                   const float* __restrict__ cosT,
                                                   const float* __restrict__ sinT) {
    int idx = blockIdx.x * 256 + threadIdx.x;
    const int qtot = B_ * S_ * HQ_ * 32;   // 2,097,152
    const int ktot = B_ * S_ * HKV_ * 32;  //   524,288
    float* base;
    int d, s;
    if (idx < qtot) {
        d = idx & 31;
        int h = (idx >> 5) & (HQ_ - 1);
        s = (idx >> 10) & (S_ - 1);
        int b = idx >> 20;
        base = Q + (size_t)(b * S_ + s) * HID_ + h * HD_;
    } else {
        idx -= qtot;
        if (idx >= ktot) return;
        d = idx & 31;
        int h = (idx >> 5) & (HKV_ - 1);
        s = (idx >> 8) & (S_ - 1);
        int b = idx >> 18;
        base = K + (size_t)(b * S_ + s) * (HKV_ * HD_) + h * HD_;
    }
    float c0 = cosT[s * HD_ + d],      s0 = sinT[s * HD_ + d];
    float c1 = cosT[s * HD_ + d + 32], s1 = sinT[s * HD_ + d + 32];
    float x0 = base[d], x1 = base[d + 32];
    base[d]      = x0 * c0 - x1 * s0;
    base[d + 32] = x1 * c1 + x0 * s1;
}

// ---------------------------------------------------------------------------
// Causal GQA attention: one 64-lane wave per (b, h, q) row.
// Phase 1: scores s_k = scale * q . K_k  (k = lane, lane+64, ...), kept in regs
// Phase 2: wave-reduce max, exp, wave-reduce sum, probs -> LDS
// Phase 3: lane = d; out[d] = (1/sum) * sum_k p_k * V[k][d]  (coalesced V)
// ---------------------------------------------------------------------------
__global__ __launch_bounds__(64) void attn_kernel(const float* __restrict__ Q,
                                                  const float* __restrict__ K,
                                                  const float* __restrict__ V,
                                                  float* __restrict__ ctx) {
    const int q    = blockIdx.x;
    const int h    = blockIdx.y;
    const int b    = blockIdx.z;
    const int lane = threadIdx.x;
    const int kv   = h >> 2;  // h / (HQ/HKV)

    __shared__ float sc[S_];
    __shared__ __align__(16) float qs[HD_];

    const float* Qrow = Q + (size_t)(b * S_ + q) * HID_ + h * HD_;
    qs[lane] = Qrow[lane];
    __syncthreads();

    const float scale = 0.125f;  // HD^-0.5
    const int nk = q + 1;
    const float* Kb = K + (size_t)b * S_ * (HKV_ * HD_) + kv * HD_;

    float sreg[16];
    float mmax = -1e30f;
    int cnt = 0;
    for (int k = lane; k < nk; k += 64, ++cnt) {
        const float4* K4 = (const float4*)(Kb + (size_t)k * (HKV_ * HD_));
        float s = 0.f;
#pragma unroll
        for (int d4 = 0; d4 < 16; ++d4) {
            float4 kvv = K4[d4];
            float4 qv  = *(const float4*)&qs[d4 * 4];
            s = fmaf(qv.x, kvv.x, s);
            s = fmaf(qv.y, kvv.y, s);
            s = fmaf(qv.z, kvv.z, s);
            s = fmaf(qv.w, kvv.w, s);
        }
        s *= scale;
        sreg[cnt] = s;
        mmax = fmaxf(mmax, s);
    }
#pragma unroll
    for (int off = 32; off; off >>= 1)
        mmax = fmaxf(mmax, __shfl_xor(mmax, off, 64));

    float lsum = 0.f;
    {
        int i = 0;
        for (int k = lane; k < nk; k += 64, ++i) {
            float p = __expf(sreg[i] - mmax);
            sc[k] = p;
            lsum += p;
        }
    }
#pragma unroll
    for (int off = 32; off; off >>= 1)
        lsum += __shfl_xor(lsum, off, 64);
    const float inv = 1.0f / lsum;
    __syncthreads();

    const float* Vb = V + (size_t)b * S_ * (HKV_ * HD_) + kv * HD_ + lane;
    float acc = 0.f;
    for (int k = 0; k < nk; ++k)
        acc = fmaf(sc[k], Vb[(size_t)k * (HKV_ * HD_)], acc);

    ctx[(size_t)(b * S_ + q) * HID_ + h * HD_ + lane] = acc * inv;
}

// ---------------------------------------------------------------------------
extern "C" void kernel_launch(void* const* d_in, const int* in_sizes, int n_in,
                              void* d_out, int out_size, void* d_ws, size_t ws_size,
                              hipStream_t stream) {
    const float* X    = (const float*)d_in[0];  // (B,S,HID)
    const float* cosT = (const float*)d_in[1];  // (S,HD)
    const float* sinT = (const float*)d_in[2];  // (S,HD)
    const float* Wq   = (const float*)d_in[3];  // (HID,HID)
    const float* Wk   = (const float*)d_in[4];  // (HID,HKV*HD)
    const float* Wv   = (const float*)d_in[5];  // (HID,HKV*HD)
    const float* Wo   = (const float*)d_in[6];  // (HID,HID)
    float* out = (float*)d_out;                 // (B,S,HID)

    const int M = B_ * S_;          // 2048
    const int NKV = HKV_ * HD_;     // 512

    char* ws = (char*)d_ws;
    float* Qb  = (float*)(ws);                                   // M*HID  = 16 MB
    float* Kb  = (float*)(ws + (size_t)M * HID_ * 4);            // M*512  =  4 MB
    float* Vb  = (float*)(ws + (size_t)M * HID_ * 4 + (size_t)M * NKV * 4);
    float* Ctx = (float*)(ws + (size_t)M * HID_ * 4 + (size_t)2 * M * NKV * 4);

    // QKV projections
    gemm_f32<<<dim3(HID_ / 64, M / 64), 256, 0, stream>>>(X, Wq, Qb, M, HID_, HID_);
    gemm_f32<<<dim3(NKV / 64, M / 64), 256, 0, stream>>>(X, Wk, Kb, M, NKV, HID_);
    gemm_f32<<<dim3(NKV / 64, M / 64), 256, 0, stream>>>(X, Wv, Vb, M, NKV, HID_);

    // RoPE on Q and K
    {
        int total = B_ * S_ * (HQ_ + HKV_) * 32;
        rope_kernel<<<(total + 255) / 256, 256, 0, stream>>>(Qb, Kb, cosT, sinT);
    }

    // Attention
    attn_kernel<<<dim3(S_, HQ_, B_), 64, 0, stream>>>(Qb, Kb, Vb, Ctx);

    // Output projection
    gemm_f32<<<dim3(HID_ / 64, M / 64), 256, 0, stream>>>(Ctx, Wo, out, M, HID_, HID_);
}

// Round 2
// 944.200 us; speedup vs baseline: 2.1640x; 2.1640x over previous
//
#include <hip/hip_runtime.h>
#include <math.h>

#define B_   2
#define S_   1024
#define HID_ 2048
#define HQ_  32
#define HKV_ 8
#define HD_  64
// n_rep = HQ_/HKV_ = 4

using short8  = __attribute__((ext_vector_type(8))) short;
using floatx4 = __attribute__((ext_vector_type(4))) float;

__device__ __forceinline__ unsigned short f2bf(float x) {
    unsigned int u = __builtin_bit_cast(unsigned int, x);
    u += 0x7FFFu + ((u >> 16) & 1u);
    return (unsigned short)(u >> 16);
}

// ---------------------------------------------------------------------------
// fp32 GEMM (unchanged from round 1): C = A(MxK) @ B(KxN), row-major.
// 64x64 tile, 256 threads, 4x4 micro-tile per thread.
// ---------------------------------------------------------------------------
__global__ __launch_bounds__(256) void gemm_f32(const float* __restrict__ A,
                                                const float* __restrict__ Bm,
                                                float* __restrict__ C,
                                                int M, int N, int K) {
    __shared__ __align__(16) float As[16][64];
    __shared__ __align__(16) float Bs[16][64];

    const int tid = threadIdx.x;
    const int bm  = blockIdx.y * 64;
    const int bn  = blockIdx.x * 64;
    const int tm  = (tid >> 4) * 4;
    const int tn  = (tid & 15) * 4;

    const int a_r = tid >> 2;
    const int a_c = (tid & 3) * 4;
    const int b_r = tid >> 4;
    const int b_c = (tid & 15) * 4;

    float acc[4][4] = {};

    for (int k0 = 0; k0 < K; k0 += 16) {
        float4 av = *(const float4*)&A[(size_t)(bm + a_r) * K + k0 + a_c];
        float4 bv = *(const float4*)&Bm[(size_t)(k0 + b_r) * N + bn + b_c];
        __syncthreads();
        As[a_c + 0][a_r] = av.x;
        As[a_c + 1][a_r] = av.y;
        As[a_c + 2][a_r] = av.z;
        As[a_c + 3][a_r] = av.w;
        *(float4*)&Bs[b_r][b_c] = bv;
        __syncthreads();
#pragma unroll
        for (int k = 0; k < 16; ++k) {
            float4 a = *(const float4*)&As[k][tm];
            float4 b = *(const float4*)&Bs[k][tn];
            float ar[4] = {a.x, a.y, a.z, a.w};
            float br[4] = {b.x, b.y, b.z, b.w};
#pragma unroll
            for (int i = 0; i < 4; ++i)
#pragma unroll
                for (int j = 0; j < 4; ++j)
                    acc[i][j] = fmaf(ar[i], br[j], acc[i][j]);
        }
    }

#pragma unroll
    for (int i = 0; i < 4; ++i) {
        float4 o = {acc[i][0], acc[i][1], acc[i][2], acc[i][3]};
        *(float4*)&C[(size_t)(bm + tm + i) * N + bn + tn] = o;
    }
}

// ---------------------------------------------------------------------------
// RoPE in-place on Q (B,S,HQ,HD) and K (B,S,HKV,HD), fp32.
// ---------------------------------------------------------------------------
__global__ __launch_bounds__(256) void rope_kernel(float* __restrict__ Q,
                                                   float* __restrict__ K,
                                                   const float* __restrict__ cosT,
                                                   const float* __restrict__ sinT) {
    int idx = blockIdx.x * 256 + threadIdx.x;
    const int qtot = B_ * S_ * HQ_ * 32;
    const int ktot = B_ * S_ * HKV_ * 32;
    float* base;
    int d, s;
    if (idx < qtot) {
        d = idx & 31;
        int h = (idx >> 5) & (HQ_ - 1);
        s = (idx >> 10) & (S_ - 1);
        int b = idx >> 20;
        base = Q + (size_t)(b * S_ + s) * HID_ + h * HD_;
    } else {
        idx -= qtot;
        if (idx >= ktot) return;
        d = idx & 31;
        int h = (idx >> 5) & (HKV_ - 1);
        s = (idx >> 8) & (S_ - 1);
        int b = idx >> 18;
        base = K + (size_t)(b * S_ + s) * (HKV_ * HD_) + h * HD_;
    }
    float c0 = cosT[s * HD_ + d],      s0 = sinT[s * HD_ + d];
    float c1 = cosT[s * HD_ + d + 32], s1 = sinT[s * HD_ + d + 32];
    float x0 = base[d], x1 = base[d + 32];
    base[d]      = x0 * c0 - x1 * s0;
    base[d + 32] = x1 * c1 + x0 * s1;
}

// ---------------------------------------------------------------------------
// Layout conversions fp32 -> bf16 (head-major) for the MFMA attention.
//   Qbf[(b*HQ+h)*S + s][d] = 0.125f * Q[b][s][h][d]   (scale folded in)
//   Kbf[(b*HKV+kv)*S + s][d] = K[b][s][kv][d]
//   Vt [(b*HKV+kv)*HD + d][s] = V[b][s][kv][d]        (transposed)
// ---------------------------------------------------------------------------
__global__ __launch_bounds__(256) void convert_q(const float* __restrict__ in,
                                                 unsigned short* __restrict__ out) {
    int tid = blockIdx.x * 256 + threadIdx.x;     // B*HQ*S*16 threads
    int d4 = tid & 15;
    int s  = (tid >> 4) & (S_ - 1);
    int h  = (tid >> 14) & (HQ_ - 1);
    int b  = tid >> 19;
    float4 v = *(const float4*)&in[((size_t)(b * S_ + s) * HQ_ + h) * HD_ + d4 * 4];
    ushort4 o = {f2bf(v.x * 0.125f), f2bf(v.y * 0.125f),
                 f2bf(v.z * 0.125f), f2bf(v.w * 0.125f)};
    *(ushort4*)&out[((size_t)(b * HQ_ + h) * S_ + s) * HD_ + d4 * 4] = o;
}

__global__ __launch_bounds__(256) void convert_k(const float* __restrict__ in,
                                                 unsigned short* __restrict__ out) {
    int tid = blockIdx.x * 256 + threadIdx.x;     // B*HKV*S*16 threads
    int d4 = tid & 15;
    int s  = (tid >> 4) & (S_ - 1);
    int kv = (tid >> 14) & (HKV_ - 1);
    int b  = tid >> 17;
    float4 v = *(const float4*)&in[((size_t)(b * S_ + s) * HKV_ + kv) * HD_ + d4 * 4];
    ushort4 o = {f2bf(v.x), f2bf(v.y), f2bf(v.z), f2bf(v.w)};
    *(ushort4*)&out[((size_t)(b * HKV_ + kv) * S_ + s) * HD_ + d4 * 4] = o;
}

__global__ __launch_bounds__(256) void convert_vt(const float* __restrict__ in,
                                                  unsigned short* __restrict__ out) {
    int tid = blockIdx.x * 256 + threadIdx.x;     // B*HKV*HD*(S/4) threads
    int s4 = tid & 255;
    int d  = (tid >> 8) & (HD_ - 1);
    int kv = (tid >> 14) & (HKV_ - 1);
    int b  = tid >> 17;
    int s  = s4 * 4;
    ushort4 o;
    o.x = f2bf(in[((size_t)(b * S_ + s + 0) * HKV_ + kv) * HD_ + d]);
    o.y = f2bf(in[((size_t)(b * S_ + s + 1) * HKV_ + kv) * HD_ + d]);
    o.z = f2bf(in[((size_t)(b * S_ + s + 2) * HKV_ + kv) * HD_ + d]);
    o.w = f2bf(in[((size_t)(b * S_ + s + 3) * HKV_ + kv) * HD_ + d]);
    *(ushort4*)&out[((size_t)(b * HKV_ + kv) * HD_ + d) * S_ + s] = o;
}

// ---------------------------------------------------------------------------
// Flash-style causal GQA attention, bf16 MFMA (16x16x32).
// Block = 256 threads = 4 waves; block owns (b, h, 64-row q-super-tile);
// wave w owns q rows [q0+16w, q0+16w+15]. K-loop over 32-col k-blocks.
// Per step: 4 QK MFMAs -> 16x32 scores (C-layout) -> online softmax ->
// P (bf16) via per-wave LDS round-trip into A-layout -> 4 PV MFMAs.
// All waves run the block-max trip count (inactive waves skip compute but
// hit barriers) so __syncthreads is uniform.
// ---------------------------------------------------------------------------
__global__ __launch_bounds__(256) void attn_mfma(const unsigned short* __restrict__ Qbf,
                                                 const unsigned short* __restrict__ Kbf,
                                                 const unsigned short* __restrict__ Vt,
                                                 float* __restrict__ Ctx) {
    const int q0   = blockIdx.x * 64;
    const int h    = blockIdx.y;
    const int b    = blockIdx.z;
    const int w    = threadIdx.x >> 6;
    const int lane = threadIdx.x & 63;
    const int col  = lane & 15;
    const int quad = lane >> 4;

    const int bh  = b * HQ_ + h;
    const int bkv = b * HKV_ + (h >> 2);

    // P staging: per-wave 16 rows x 32 cols bf16, row stride 40 (pad -> only
    // free 2-way bank conflicts on both the scattered write and b128 read).
    __shared__ __align__(16) unsigned short sPb[4][16 * 40];

    // Q fragments (A-layout, m=lane&15, k=quad*8+j), two 32-wide d-chunks.
    const unsigned short* qrow =
        Qbf + ((size_t)bh * S_ + q0 + 16 * w + col) * HD_;
    short8 aq[2];
    aq[0] = *(const short8*)&qrow[0  + quad * 8];
    aq[1] = *(const short8*)&qrow[32 + quad * 8];

    floatx4 acc_o[4] = {};            // O in C-layout, 4 n-tiles over HD=64
    float m_i[4], l_i[4];
#pragma unroll
    for (int r = 0; r < 4; ++r) { m_i[r] = -1e30f; l_i[r] = 0.f; }

    int qg[4];
#pragma unroll
    for (int r = 0; r < 4; ++r) qg[r] = q0 + 16 * w + quad * 4 + r;
    const int q_hi = q0 + 16 * w + 15;

    const unsigned short* Kbase = Kbf + (size_t)bkv * S_ * HD_;
    const unsigned short* Vbase = Vt + (size_t)bkv * HD_ * S_;
    unsigned short* myP = sPb[w];

    const int kend = q0 + 64;
    for (int k0 = 0; k0 < kend; k0 += 32) {
        const bool active = (k0 <= q_hi);
        if (active) {
            // ---- QK^T: scores 16x32 as two 16x16 C-frags ----
            floatx4 sc[2];
#pragma unroll
            for (int t = 0; t < 2; ++t) {
                const unsigned short* krow =
                    Kbase + (size_t)(k0 + 16 * t + col) * HD_;
                short8 kb0 = *(const short8*)&krow[0  + quad * 8];
                short8 kb1 = *(const short8*)&krow[32 + quad * 8];
                floatx4 z = {0.f, 0.f, 0.f, 0.f};
                z = __builtin_amdgcn_mfma_f32_16x16x32_bf16(aq[0], kb0, z, 0, 0, 0);
                z = __builtin_amdgcn_mfma_f32_16x16x32_bf16(aq[1], kb1, z, 0, 0, 0);
                sc[t] = z;
            }
            // ---- causal mask ----
#pragma unroll
            for (int t = 0; t < 2; ++t) {
                int kg = k0 + 16 * t + col;
#pragma unroll
                for (int r = 0; r < 4; ++r)
                    if (kg > qg[r]) sc[t][r] = -1e30f;
            }
            // ---- online softmax (rows live across the 16-lane quad group) --
            float p0[4], p1[4], alpha[4];
#pragma unroll
            for (int r = 0; r < 4; ++r) {
                float v = fmaxf(sc[0][r], sc[1][r]);
#pragma unroll
                for (int off = 1; off < 16; off <<= 1)
                    v = fmaxf(v, __shfl_xor(v, off, 64));
                float mn = fmaxf(m_i[r], v);
                alpha[r] = __expf(m_i[r] - mn);
                m_i[r] = mn;
                p0[r] = __expf(sc[0][r] - mn);
                p1[r] = __expf(sc[1][r] - mn);
                float s = p0[r] + p1[r];
#pragma unroll
                for (int off = 1; off < 16; off <<= 1)
                    s += __shfl_xor(s, off, 64);
                l_i[r] = l_i[r] * alpha[r] + s;
            }
#pragma unroll
            for (int nt = 0; nt < 4; ++nt)
#pragma unroll
                for (int r = 0; r < 4; ++r)
                    acc_o[nt][r] *= alpha[r];
            // ---- P (C-layout) -> LDS bf16 ----
#pragma unroll
            for (int r = 0; r < 4; ++r) {
                myP[(quad * 4 + r) * 40 + col]      = f2bf(p0[r]);
                myP[(quad * 4 + r) * 40 + 16 + col] = f2bf(p1[r]);
            }
        }
        __syncthreads();
        if (active) {
            // ---- P in A-layout + V B-frags -> 4 PV MFMAs ----
            short8 pa = *(const short8*)&myP[col * 40 + quad * 8];
#pragma unroll
            for (int nt = 0; nt < 4; ++nt) {
                short8 vb = *(const short8*)
                    &Vbase[(size_t)(nt * 16 + col) * S_ + k0 + quad * 8];
                acc_o[nt] =
                    __builtin_amdgcn_mfma_f32_16x16x32_bf16(pa, vb, acc_o[nt], 0, 0, 0);
            }
        }
        __syncthreads();
    }

    // ---- epilogue: divide by l, write fp32 ctx (B,S,HID) ----
    float inv[4];
#pragma unroll
    for (int r = 0; r < 4; ++r) inv[r] = 1.0f / l_i[r];
#pragma unroll
    for (int nt = 0; nt < 4; ++nt)
#pragma unroll
        for (int r = 0; r < 4; ++r)
            Ctx[(size_t)(b * S_ + qg[r]) * HID_ + h * HD_ + nt * 16 + col] =
                acc_o[nt][r] * inv[r];
}

// ---------------------------------------------------------------------------
extern "C" void kernel_launch(void* const* d_in, const int* in_sizes, int n_in,
                              void* d_out, int out_size, void* d_ws, size_t ws_size,
                              hipStream_t stream) {
    const float* X    = (const float*)d_in[0];
    const float* cosT = (const float*)d_in[1];
    const float* sinT = (const float*)d_in[2];
    const float* Wq   = (const float*)d_in[3];
    const float* Wk   = (const float*)d_in[4];
    const float* Wv   = (const float*)d_in[5];
    const float* Wo   = (const float*)d_in[6];
    float* out = (float*)d_out;

    const int M   = B_ * S_;        // 2048
    const int NKV = HKV_ * HD_;     // 512

    // Workspace layout (peak 36 MB):
    //   [Qb fp32 16MB][Kb fp32 4MB][Vb fp32 4MB][Qbf 8MB][Kbf 2MB][Vt 2MB]
    //   Ctx fp32 (16MB) aliases Qb — written only after convert_q consumed Qb.
    char* ws = (char*)d_ws;
    float* Qb  = (float*)(ws);
    float* Kb  = (float*)(ws + 16u * 1024 * 1024);
    float* Vb  = (float*)(ws + 20u * 1024 * 1024);
    unsigned short* Qbf = (unsigned short*)(ws + 24u * 1024 * 1024);
    unsigned short* Kbf = (unsigned short*)(ws + 32u * 1024 * 1024);
    unsigned short* Vt  = (unsigned short*)(ws + 34u * 1024 * 1024);
    float* Ctx = (float*)(ws);      // alias Qb

    // QKV projections (fp32)
    gemm_f32<<<dim3(HID_ / 64, M / 64), 256, 0, stream>>>(X, Wq, Qb, M, HID_, HID_);
    gemm_f32<<<dim3(NKV / 64, M / 64), 256, 0, stream>>>(X, Wk, Kb, M, NKV, HID_);
    gemm_f32<<<dim3(NKV / 64, M / 64), 256, 0, stream>>>(X, Wv, Vb, M, NKV, HID_);

    // RoPE on Q and K (fp32, in place)
    {
        int total = B_ * S_ * (HQ_ + HKV_) * 32;
        rope_kernel<<<(total + 255) / 256, 256, 0, stream>>>(Qb, Kb, cosT, sinT);
    }

    // bf16 conversions (scale folded into Q)
    convert_q <<<B_ * HQ_ * S_ * 16 / 256, 256, 0, stream>>>(Qb, Qbf);
    convert_k <<<B_ * HKV_ * S_ * 16 / 256, 256, 0, stream>>>(Kb, Kbf);
    convert_vt<<<B_ * HKV_ * HD_ * (S_ / 4) / 256, 256, 0, stream>>>(Vb, Vt);

    // Flash attention (bf16 MFMA) -> Ctx fp32
    attn_mfma<<<dim3(S_ / 64, HQ_, B_), 256, 0, stream>>>(Qbf, Kbf, Vt, Ctx);

    // Output projection (fp32)
    gemm_f32<<<dim3(HID_ / 64, M / 64), 256, 0, stream>>>(Ctx, Wo, out, M, HID_, HID_);
}

// Round 3
// 344.163 us; speedup vs baseline: 5.9369x; 2.7435x over previous
//
#include <hip/hip_runtime.h>
#include <math.h>

#define B_   2
#define S_   1024
#define HID_ 2048
#define HQ_  32
#define HKV_ 8
#define HD_  64
#define NQKV 3072   // HID + 2*HKV*HD

using short8  = __attribute__((ext_vector_type(8))) short;
using floatx4 = __attribute__((ext_vector_type(4))) float;

__device__ __forceinline__ unsigned short f2bf(float x) {
    unsigned int u = __builtin_bit_cast(unsigned int, x);
    u += 0x7FFFu + ((u >> 16) & 1u);
    return (unsigned short)(u >> 16);
}
__device__ __forceinline__ float bf2f(unsigned short u) {
    return __builtin_bit_cast(float, (unsigned int)u << 16);
}

__device__ __forceinline__ void gl_lds16(const unsigned short* g, unsigned short* l) {
    __builtin_amdgcn_global_load_lds(
        (const __attribute__((address_space(1))) void*)g,
        (__attribute__((address_space(3))) void*)l, 16, 0, 0);
}

// ---------------------------------------------------------------------------
// bf16 MFMA GEMM: C(MxN) = A(MxK) @ Bt(NxK)^T.  A,Bt bf16; C fp32 or bf16.
// 128x128 tile, BK=32, 256 threads = 4 waves in 2x2 of 64x64 sub-tiles.
// Staging via global_load_lds width-16 (m97 pattern): per K-step each wave
// stages 2x16 rows of A and of Bt; LDS layout [row][k] with k contiguous (32).
// M, N multiples of 128; K multiple of 32.
// ---------------------------------------------------------------------------
template <bool BF16OUT>
__global__ __launch_bounds__(256) void gemm_mfma(const unsigned short* __restrict__ A,
                                                 const unsigned short* __restrict__ Bt,
                                                 void* __restrict__ Cv,
                                                 int M, int N, int K) {
    __shared__ __align__(16) unsigned short As[128 * 32];
    __shared__ __align__(16) unsigned short Bs[128 * 32];

    const int tid  = threadIdx.x;
    const int w    = tid >> 6;
    const int lane = tid & 63;
    const int col  = lane & 15;
    const int quad = lane >> 4;
    const int m0 = blockIdx.y * 128;
    const int n0 = blockIdx.x * 128;
    const int wm = (w >> 1) * 64;
    const int wn = (w & 1) * 64;

    // staging: lane -> (row = lane>>2, koff = (lane&3)*8); wave covers 16 rows
    const int srow = lane >> 2;
    const int skof = (lane & 3) * 8;
    const unsigned short* Ag = A  + (size_t)(m0 + srow) * K + skof;
    const unsigned short* Bg = Bt + (size_t)(n0 + srow) * K + skof;
    const int rb = w * 16;

    floatx4 acc[4][4] = {};

    for (int k0 = 0; k0 < K; k0 += 32) {
        gl_lds16(Ag + (size_t)(rb     ) * K + k0, &As[(rb     ) * 32]);
        gl_lds16(Ag + (size_t)(rb + 64) * K + k0, &As[(rb + 64) * 32]);
        gl_lds16(Bg + (size_t)(rb     ) * K + k0, &Bs[(rb     ) * 32]);
        gl_lds16(Bg + (size_t)(rb + 64) * K + k0, &Bs[(rb + 64) * 32]);
        __syncthreads();

        short8 af[4], bfr[4];
#pragma unroll
        for (int i = 0; i < 4; ++i)
            af[i] = *(const short8*)&As[(wm + i * 16 + col) * 32 + quad * 8];
#pragma unroll
        for (int j = 0; j < 4; ++j)
            bfr[j] = *(const short8*)&Bs[(wn + j * 16 + col) * 32 + quad * 8];
#pragma unroll
        for (int i = 0; i < 4; ++i)
#pragma unroll
            for (int j = 0; j < 4; ++j)
                acc[i][j] = __builtin_amdgcn_mfma_f32_16x16x32_bf16(
                    af[i], bfr[j], acc[i][j], 0, 0, 0);
        __syncthreads();
    }

#pragma unroll
    for (int i = 0; i < 4; ++i)
#pragma unroll
        for (int j = 0; j < 4; ++j)
#pragma unroll
            for (int r = 0; r < 4; ++r) {
                size_t off = (size_t)(m0 + wm + i * 16 + quad * 4 + r) * N
                           + (n0 + wn + j * 16 + col);
                if constexpr (BF16OUT)
                    ((unsigned short*)Cv)[off] = f2bf(acc[i][j][r]);
                else
                    ((float*)Cv)[off] = acc[i][j][r];
            }
}

// ---------------------------------------------------------------------------
// fp32 -> bf16 elementwise (X)
// ---------------------------------------------------------------------------
__global__ __launch_bounds__(256) void convert_x(const float* __restrict__ in,
                                                 unsigned short* __restrict__ out) {
    int tid = blockIdx.x * 256 + threadIdx.x;
    float4 v = *(const float4*)&in[(size_t)tid * 4];
    ushort4 o = {f2bf(v.x), f2bf(v.y), f2bf(v.z), f2bf(v.w)};
    *(ushort4*)&out[(size_t)tid * 4] = o;
}

// ---------------------------------------------------------------------------
// W (KxN fp32) -> WT (NxK bf16), 32x32 LDS-tiled transpose.
// ---------------------------------------------------------------------------
__global__ __launch_bounds__(256) void transpose_w(const float* __restrict__ W,
                                                   unsigned short* __restrict__ WT,
                                                   int K, int N) {
    __shared__ float tile[32][33];
    const int tk0 = blockIdx.y * 32;
    const int tn0 = blockIdx.x * 32;
    const int r  = threadIdx.x >> 3;
    const int c4 = (threadIdx.x & 7) * 4;
    float4 v = *(const float4*)&W[(size_t)(tk0 + r) * N + tn0 + c4];
    tile[r][c4 + 0] = v.x;
    tile[r][c4 + 1] = v.y;
    tile[r][c4 + 2] = v.z;
    tile[r][c4 + 3] = v.w;
    __syncthreads();
    ushort4 o = {f2bf(tile[c4 + 0][r]), f2bf(tile[c4 + 1][r]),
                 f2bf(tile[c4 + 2][r]), f2bf(tile[c4 + 3][r])};
    *(ushort4*)&WT[(size_t)(tn0 + r) * K + tk0 + c4] = o;
}

// ---------------------------------------------------------------------------
// Fused RoPE + layout conversion from QKVbf (B*S rows, 3072 bf16 cols).
//   Qbf[(b*HQ+h)*S + s][d]  = rope(q)[d] * 0.125
//   Kbf[(b*HKV+kv)*S + s][d] = rope(k)[d]
//   Vt [(b*HKV+kv)*HD + d][s] = v[d]
// ---------------------------------------------------------------------------
__global__ __launch_bounds__(256) void convert_q(const unsigned short* __restrict__ QKV,
                                                 const float* __restrict__ cosT,
                                                 const float* __restrict__ sinT,
                                                 unsigned short* __restrict__ out) {
    int tid = blockIdx.x * 256 + threadIdx.x;   // B*S*HQ*32
    int d = tid & 31;
    int h = (tid >> 5) & (HQ_ - 1);
    int s = (tid >> 10) & (S_ - 1);
    int b = tid >> 20;
    const unsigned short* row = QKV + (size_t)(b * S_ + s) * NQKV + h * HD_;
    float x0 = bf2f(row[d]), x1 = bf2f(row[d + 32]);
    float c0 = cosT[s * HD_ + d],      s0 = sinT[s * HD_ + d];
    float c1 = cosT[s * HD_ + d + 32], s1 = sinT[s * HD_ + d + 32];
    unsigned short* orow = out + ((size_t)(b * HQ_ + h) * S_ + s) * HD_;
    orow[d]      = f2bf((x0 * c0 - x1 * s0) * 0.125f);
    orow[d + 32] = f2bf((x1 * c1 + x0 * s1) * 0.125f);
}

__global__ __launch_bounds__(256) void convert_k(const unsigned short* __restrict__ QKV,
                                                 const float* __restrict__ cosT,
                                                 const float* __restrict__ sinT,
                                                 unsigned short* __restrict__ out) {
    int tid = blockIdx.x * 256 + threadIdx.x;   // B*S*HKV*32
    int d  = tid & 31;
    int kv = (tid >> 5) & (HKV_ - 1);
    int s  = (tid >> 8) & (S_ - 1);
    int b  = tid >> 18;
    const unsigned short* row = QKV + (size_t)(b * S_ + s) * NQKV + HID_ + kv * HD_;
    float x0 = bf2f(row[d]), x1 = bf2f(row[d + 32]);
    float c0 = cosT[s * HD_ + d],      s0 = sinT[s * HD_ + d];
    float c1 = cosT[s * HD_ + d + 32], s1 = sinT[s * HD_ + d + 32];
    unsigned short* orow = out + ((size_t)(b * HKV_ + kv) * S_ + s) * HD_;
    orow[d]      = f2bf(x0 * c0 - x1 * s0);
    orow[d + 32] = f2bf(x1 * c1 + x0 * s1);
}

__global__ __launch_bounds__(256) void convert_vt(const unsigned short* __restrict__ QKV,
                                                  unsigned short* __restrict__ out) {
    int tid = blockIdx.x * 256 + threadIdx.x;   // B*HKV*HD*(S/4)
    int s4 = tid & 255;
    int d  = (tid >> 8) & (HD_ - 1);
    int kv = (tid >> 14) & (HKV_ - 1);
    int b  = tid >> 17;
    int s  = s4 * 4;
    const unsigned short* base = QKV + (size_t)b * S_ * NQKV + HID_ + 512 + kv * HD_ + d;
    ushort4 o;
    o.x = base[(size_t)(s + 0) * NQKV];
    o.y = base[(size_t)(s + 1) * NQKV];
    o.z = base[(size_t)(s + 2) * NQKV];
    o.w = base[(size_t)(s + 3) * NQKV];
    *(ushort4*)&out[((size_t)(b * HKV_ + kv) * HD_ + d) * S_ + s] = o;
}

// ---------------------------------------------------------------------------
// Flash-style causal GQA attention, bf16 MFMA (16x16x32). Unchanged from
// round 2 except the context is written as bf16 (feeds the MFMA Wo GEMM).
// ---------------------------------------------------------------------------
__global__ __launch_bounds__(256) void attn_mfma(const unsigned short* __restrict__ Qbf,
                                                 const unsigned short* __restrict__ Kbf,
                                                 const unsigned short* __restrict__ Vt,
                                                 unsigned short* __restrict__ Ctx) {
    const int q0   = blockIdx.x * 64;
    const int h    = blockIdx.y;
    const int b    = blockIdx.z;
    const int w    = threadIdx.x >> 6;
    const int lane = threadIdx.x & 63;
    const int col  = lane & 15;
    const int quad = lane >> 4;

    const int bh  = b * HQ_ + h;
    const int bkv = b * HKV_ + (h >> 2);

    __shared__ __align__(16) unsigned short sPb[4][16 * 40];

    const unsigned short* qrow =
        Qbf + ((size_t)bh * S_ + q0 + 16 * w + col) * HD_;
    short8 aq[2];
    aq[0] = *(const short8*)&qrow[0  + quad * 8];
    aq[1] = *(const short8*)&qrow[32 + quad * 8];

    floatx4 acc_o[4] = {};
    float m_i[4], l_i[4];
#pragma unroll
    for (int r = 0; r < 4; ++r) { m_i[r] = -1e30f; l_i[r] = 0.f; }

    int qg[4];
#pragma unroll
    for (int r = 0; r < 4; ++r) qg[r] = q0 + 16 * w + quad * 4 + r;
    const int q_hi = q0 + 16 * w + 15;

    const unsigned short* Kbase = Kbf + (size_t)bkv * S_ * HD_;
    const unsigned short* Vbase = Vt + (size_t)bkv * HD_ * S_;
    unsigned short* myP = sPb[w];

    const int kend = q0 + 64;
    for (int k0 = 0; k0 < kend; k0 += 32) {
        const bool active = (k0 <= q_hi);
        if (active) {
            floatx4 sc[2];
#pragma unroll
            for (int t = 0; t < 2; ++t) {
                const unsigned short* krow =
                    Kbase + (size_t)(k0 + 16 * t + col) * HD_;
                short8 kb0 = *(const short8*)&krow[0  + quad * 8];
                short8 kb1 = *(const short8*)&krow[32 + quad * 8];
                floatx4 z = {0.f, 0.f, 0.f, 0.f};
                z = __builtin_amdgcn_mfma_f32_16x16x32_bf16(aq[0], kb0, z, 0, 0, 0);
                z = __builtin_amdgcn_mfma_f32_16x16x32_bf16(aq[1], kb1, z, 0, 0, 0);
                sc[t] = z;
            }
#pragma unroll
            for (int t = 0; t < 2; ++t) {
                int kg = k0 + 16 * t + col;
#pragma unroll
                for (int r = 0; r < 4; ++r)
                    if (kg > qg[r]) sc[t][r] = -1e30f;
            }
            float p0[4], p1[4], alpha[4];
#pragma unroll
            for (int r = 0; r < 4; ++r) {
                float v = fmaxf(sc[0][r], sc[1][r]);
#pragma unroll
                for (int off = 1; off < 16; off <<= 1)
                    v = fmaxf(v, __shfl_xor(v, off, 64));
                float mn = fmaxf(m_i[r], v);
                alpha[r] = __expf(m_i[r] - mn);
                m_i[r] = mn;
                p0[r] = __expf(sc[0][r] - mn);
                p1[r] = __expf(sc[1][r] - mn);
                float s = p0[r] + p1[r];
#pragma unroll
                for (int off = 1; off < 16; off <<= 1)
                    s += __shfl_xor(s, off, 64);
                l_i[r] = l_i[r] * alpha[r] + s;
            }
#pragma unroll
            for (int nt = 0; nt < 4; ++nt)
#pragma unroll
                for (int r = 0; r < 4; ++r)
                    acc_o[nt][r] *= alpha[r];
#pragma unroll
            for (int r = 0; r < 4; ++r) {
                myP[(quad * 4 + r) * 40 + col]      = f2bf(p0[r]);
                myP[(quad * 4 + r) * 40 + 16 + col] = f2bf(p1[r]);
            }
        }
        __syncthreads();
        if (active) {
            short8 pa = *(const short8*)&myP[col * 40 + quad * 8];
#pragma unroll
            for (int nt = 0; nt < 4; ++nt) {
                short8 vb = *(const short8*)
                    &Vbase[(size_t)(nt * 16 + col) * S_ + k0 + quad * 8];
                acc_o[nt] =
                    __builtin_amdgcn_mfma_f32_16x16x32_bf16(pa, vb, acc_o[nt], 0, 0, 0);
            }
        }
        __syncthreads();
    }

    float inv[4];
#pragma unroll
    for (int r = 0; r < 4; ++r) inv[r] = 1.0f / l_i[r];
#pragma unroll
    for (int nt = 0; nt < 4; ++nt)
#pragma unroll
        for (int r = 0; r < 4; ++r)
            Ctx[(size_t)(b * S_ + qg[r]) * HID_ + h * HD_ + nt * 16 + col] =
                f2bf(acc_o[nt][r] * inv[r]);
}

// ---------------------------------------------------------------------------
extern "C" void kernel_launch(void* const* d_in, const int* in_sizes, int n_in,
                              void* d_out, int out_size, void* d_ws, size_t ws_size,
                              hipStream_t stream) {
    const float* X    = (const float*)d_in[0];
    const float* cosT = (const float*)d_in[1];
    const float* sinT = (const float*)d_in[2];
    const float* Wq   = (const float*)d_in[3];
    const float* Wk   = (const float*)d_in[4];
    const float* Wv   = (const float*)d_in[5];
    const float* Wo   = (const float*)d_in[6];

    const int M = B_ * S_;          // 2048
    const size_t MB = 1024u * 1024u;

    // Workspace (28 MB peak) with lifetime-based aliasing:
    //   [0,8):   Xbf (dead after QKV GEMM)      -> Qbf
    //   [8,20):  WcatT (dead after QKV GEMM)    -> Kbf @8, Vt @10, Ctxbf @12
    //   [20,28): WoT (live to the end)
    //   QKVbf (12 MB) lives in d_out (16 MB), dead before the final GEMM
    //   overwrites d_out.
    char* ws = (char*)d_ws;
    unsigned short* Xbf   = (unsigned short*)(ws);
    unsigned short* Qbf   = (unsigned short*)(ws);
    unsigned short* WcatT = (unsigned short*)(ws + 8 * MB);
    unsigned short* Kbf   = (unsigned short*)(ws + 8 * MB);
    unsigned short* Vt    = (unsigned short*)(ws + 10 * MB);
    unsigned short* Ctxbf = (unsigned short*)(ws + 12 * MB);
    unsigned short* WoT   = (unsigned short*)(ws + 20 * MB);
    unsigned short* QKVbf = (unsigned short*)d_out;
    float* out = (float*)d_out;

    // X -> bf16
    convert_x<<<(M * HID_ / 4) / 256, 256, 0, stream>>>(X, Xbf);

    // Weights -> bf16 transposed; Wq|Wk|Wv concatenated as (3072 x 2048)
    transpose_w<<<dim3(HID_ / 32, HID_ / 32), 256, 0, stream>>>(Wq, WcatT, HID_, HID_);
    transpose_w<<<dim3(512 / 32, HID_ / 32), 256, 0, stream>>>(
        Wk, WcatT + (size_t)HID_ * HID_, HID_, 512);
    transpose_w<<<dim3(512 / 32, HID_ / 32), 256, 0, stream>>>(
        Wv, WcatT + (size_t)(HID_ + 512) * HID_, HID_, 512);
    transpose_w<<<dim3(HID_ / 32, HID_ / 32), 256, 0, stream>>>(Wo, WoT, HID_, HID_);

    // Fused QKV projection (bf16 MFMA) -> bf16 QKV in d_out scratch
    gemm_mfma<true><<<dim3(NQKV / 128, M / 128), 256, 0, stream>>>(
        Xbf, WcatT, QKVbf, M, NQKV, HID_);

    // Fused RoPE + layout conversion
    convert_q <<<B_ * S_ * HQ_ * 32 / 256, 256, 0, stream>>>(QKVbf, cosT, sinT, Qbf);
    convert_k <<<B_ * S_ * HKV_ * 32 / 256, 256, 0, stream>>>(QKVbf, cosT, sinT, Kbf);
    convert_vt<<<B_ * HKV_ * HD_ * (S_ / 4) / 256, 256, 0, stream>>>(QKVbf, Vt);

    // Flash attention (bf16 MFMA) -> bf16 context
    attn_mfma<<<dim3(S_ / 64, HQ_, B_), 256, 0, stream>>>(Qbf, Kbf, Vt, Ctxbf);

    // Output projection (bf16 MFMA) -> fp32 out
    gemm_mfma<false><<<dim3(HID_ / 128, M / 128), 256, 0, stream>>>(
        Ctxbf, WoT, out, M, HID_, HID_);
}

// Round 4
// 335.262 us; speedup vs baseline: 6.0945x; 1.0265x over previous
//
#include <hip/hip_runtime.h>
#include <math.h>

#define B_   2
#define S_   1024
#define HID_ 2048
#define HQ_  32
#define HKV_ 8
#define HD_  64
#define NQKV 3072   // HID + 2*HKV*HD

using short8  = __attribute__((ext_vector_type(8))) short;
using floatx4 = __attribute__((ext_vector_type(4))) float;

__device__ __forceinline__ unsigned short f2bf(float x) {
    unsigned int u = __builtin_bit_cast(unsigned int, x);
    u += 0x7FFFu + ((u >> 16) & 1u);
    return (unsigned short)(u >> 16);
}
__device__ __forceinline__ float bf2f(unsigned short u) {
    return __builtin_bit_cast(float, (unsigned int)u << 16);
}

__device__ __forceinline__ void gl_lds16(const unsigned short* g, unsigned short* l) {
    __builtin_amdgcn_global_load_lds(
        (const __attribute__((address_space(1))) void*)g,
        (__attribute__((address_space(3))) void*)l, 16, 0, 0);
}

// ---------------------------------------------------------------------------
// bf16 MFMA GEMM (unchanged from round 3): C(MxN) = A(MxK) @ Bt(NxK)^T.
// 128x128 tile, BK=32, 256 threads = 4 waves in 2x2 of 64x64 sub-tiles.
// ---------------------------------------------------------------------------
template <bool BF16OUT>
__global__ __launch_bounds__(256) void gemm_mfma(const unsigned short* __restrict__ A,
                                                 const unsigned short* __restrict__ Bt,
                                                 void* __restrict__ Cv,
                                                 int M, int N, int K) {
    __shared__ __align__(16) unsigned short As[128 * 32];
    __shared__ __align__(16) unsigned short Bs[128 * 32];

    const int tid  = threadIdx.x;
    const int w    = tid >> 6;
    const int lane = tid & 63;
    const int col  = lane & 15;
    const int quad = lane >> 4;
    const int m0 = blockIdx.y * 128;
    const int n0 = blockIdx.x * 128;
    const int wm = (w >> 1) * 64;
    const int wn = (w & 1) * 64;

    const int srow = lane >> 2;
    const int skof = (lane & 3) * 8;
    const unsigned short* Ag = A  + (size_t)(m0 + srow) * K + skof;
    const unsigned short* Bg = Bt + (size_t)(n0 + srow) * K + skof;
    const int rb = w * 16;

    floatx4 acc[4][4] = {};

    for (int k0 = 0; k0 < K; k0 += 32) {
        gl_lds16(Ag + (size_t)(rb     ) * K + k0, &As[(rb     ) * 32]);
        gl_lds16(Ag + (size_t)(rb + 64) * K + k0, &As[(rb + 64) * 32]);
        gl_lds16(Bg + (size_t)(rb     ) * K + k0, &Bs[(rb     ) * 32]);
        gl_lds16(Bg + (size_t)(rb + 64) * K + k0, &Bs[(rb + 64) * 32]);
        __syncthreads();

        short8 af[4], bfr[4];
#pragma unroll
        for (int i = 0; i < 4; ++i)
            af[i] = *(const short8*)&As[(wm + i * 16 + col) * 32 + quad * 8];
#pragma unroll
        for (int j = 0; j < 4; ++j)
            bfr[j] = *(const short8*)&Bs[(wn + j * 16 + col) * 32 + quad * 8];
#pragma unroll
        for (int i = 0; i < 4; ++i)
#pragma unroll
            for (int j = 0; j < 4; ++j)
                acc[i][j] = __builtin_amdgcn_mfma_f32_16x16x32_bf16(
                    af[i], bfr[j], acc[i][j], 0, 0, 0);
        __syncthreads();
    }

#pragma unroll
    for (int i = 0; i < 4; ++i)
#pragma unroll
        for (int j = 0; j < 4; ++j)
#pragma unroll
            for (int r = 0; r < 4; ++r) {
                size_t off = (size_t)(m0 + wm + i * 16 + quad * 4 + r) * N
                           + (n0 + wn + j * 16 + col);
                if constexpr (BF16OUT)
                    ((unsigned short*)Cv)[off] = f2bf(acc[i][j][r]);
                else
                    ((float*)Cv)[off] = acc[i][j][r];
            }
}

// ---------------------------------------------------------------------------
// fp32 -> bf16 elementwise (X)
// ---------------------------------------------------------------------------
__global__ __launch_bounds__(256) void convert_x(const float* __restrict__ in,
                                                 unsigned short* __restrict__ out) {
    int tid = blockIdx.x * 256 + threadIdx.x;
    float4 v = *(const float4*)&in[(size_t)tid * 4];
    ushort4 o = {f2bf(v.x), f2bf(v.y), f2bf(v.z), f2bf(v.w)};
    *(ushort4*)&out[(size_t)tid * 4] = o;
}

// ---------------------------------------------------------------------------
// All 4 weight transposes in ONE kernel (fp32 KxN -> bf16 NxK), 32x32 tiles.
// Block ranges: [0,4096) Wq  [4096,5120) Wk  [5120,6144) Wv  [6144,10240) Wo.
// K = 2048 for all.
// ---------------------------------------------------------------------------
__global__ __launch_bounds__(256) void transpose_all(const float* __restrict__ Wq,
                                                     const float* __restrict__ Wk,
                                                     const float* __restrict__ Wv,
                                                     const float* __restrict__ Wo,
                                                     unsigned short* __restrict__ WcatT,
                                                     unsigned short* __restrict__ WoT) {
    __shared__ float tile[32][33];
    int bid = blockIdx.x;
    const float* W;
    unsigned short* WT;
    int N, tn0, tk0;
    if (bid < 4096) {
        W = Wq; WT = WcatT; N = HID_;
        tn0 = (bid & 63) * 32; tk0 = (bid >> 6) * 32;
    } else if (bid < 5120) {
        bid -= 4096;
        W = Wk; WT = WcatT + (size_t)HID_ * HID_; N = 512;
        tn0 = (bid & 15) * 32; tk0 = (bid >> 4) * 32;
    } else if (bid < 6144) {
        bid -= 5120;
        W = Wv; WT = WcatT + (size_t)(HID_ + 512) * HID_; N = 512;
        tn0 = (bid & 15) * 32; tk0 = (bid >> 4) * 32;
    } else {
        bid -= 6144;
        W = Wo; WT = WoT; N = HID_;
        tn0 = (bid & 63) * 32; tk0 = (bid >> 6) * 32;
    }
    const int r  = threadIdx.x >> 3;
    const int c4 = (threadIdx.x & 7) * 4;
    float4 v = *(const float4*)&W[(size_t)(tk0 + r) * N + tn0 + c4];
    tile[r][c4 + 0] = v.x;
    tile[r][c4 + 1] = v.y;
    tile[r][c4 + 2] = v.z;
    tile[r][c4 + 3] = v.w;
    __syncthreads();
    ushort4 o = {f2bf(tile[c4 + 0][r]), f2bf(tile[c4 + 1][r]),
                 f2bf(tile[c4 + 2][r]), f2bf(tile[c4 + 3][r])};
    *(ushort4*)&WT[(size_t)(tn0 + r) * HID_ + tk0 + c4] = o;
}

// ---------------------------------------------------------------------------
// Fused RoPE + layout conversion, all three outputs in ONE kernel.
// tid ranges: Q (2,097,152) | K (524,288) | V^T (262,144).
// ---------------------------------------------------------------------------
__global__ __launch_bounds__(256) void convert_qkv(const unsigned short* __restrict__ QKV,
                                                   const float* __restrict__ cosT,
                                                   const float* __restrict__ sinT,
                                                   unsigned short* __restrict__ Qbf,
                                                   unsigned short* __restrict__ Kbf,
                                                   unsigned short* __restrict__ Vt) {
    int tid = blockIdx.x * 256 + threadIdx.x;
    const int NQ = B_ * S_ * HQ_ * 32;
    const int NK = B_ * S_ * HKV_ * 32;
    if (tid < NQ) {
        int d = tid & 31;
        int h = (tid >> 5) & (HQ_ - 1);
        int s = (tid >> 10) & (S_ - 1);
        int b = tid >> 20;
        const unsigned short* row = QKV + (size_t)(b * S_ + s) * NQKV + h * HD_;
        float x0 = bf2f(row[d]), x1 = bf2f(row[d + 32]);
        float c0 = cosT[s * HD_ + d],      s0 = sinT[s * HD_ + d];
        float c1 = cosT[s * HD_ + d + 32], s1 = sinT[s * HD_ + d + 32];
        unsigned short* orow = Qbf + ((size_t)(b * HQ_ + h) * S_ + s) * HD_;
        orow[d]      = f2bf((x0 * c0 - x1 * s0) * 0.125f);
        orow[d + 32] = f2bf((x1 * c1 + x0 * s1) * 0.125f);
    } else if (tid < NQ + NK) {
        tid -= NQ;
        int d  = tid & 31;
        int kv = (tid >> 5) & (HKV_ - 1);
        int s  = (tid >> 8) & (S_ - 1);
        int b  = tid >> 18;
        const unsigned short* row = QKV + (size_t)(b * S_ + s) * NQKV + HID_ + kv * HD_;
        float x0 = bf2f(row[d]), x1 = bf2f(row[d + 32]);
        float c0 = cosT[s * HD_ + d],      s0 = sinT[s * HD_ + d];
        float c1 = cosT[s * HD_ + d + 32], s1 = sinT[s * HD_ + d + 32];
        unsigned short* orow = Kbf + ((size_t)(b * HKV_ + kv) * S_ + s) * HD_;
        orow[d]      = f2bf(x0 * c0 - x1 * s0);
        orow[d + 32] = f2bf(x1 * c1 + x0 * s1);
    } else {
        tid -= NQ + NK;
        int s4 = tid & 255;
        int d  = (tid >> 8) & (HD_ - 1);
        int kv = (tid >> 14) & (HKV_ - 1);
        int b  = tid >> 17;
        int s  = s4 * 4;
        const unsigned short* base =
            QKV + (size_t)b * S_ * NQKV + HID_ + 512 + kv * HD_ + d;
        ushort4 o;
        o.x = base[(size_t)(s + 0) * NQKV];
        o.y = base[(size_t)(s + 1) * NQKV];
        o.z = base[(size_t)(s + 2) * NQKV];
        o.w = base[(size_t)(s + 3) * NQKV];
        *(ushort4*)&Vt[((size_t)(b * HKV_ + kv) * HD_ + d) * S_ + s] = o;
    }
}

// ---------------------------------------------------------------------------
// Flash-style causal GQA attention, bf16 MFMA, KQ^T orientation.
// Block = 4 waves; wave w owns q rows [q0+16w, q0+16w+15] and runs its own
// K-loop (64 keys/step) with NO barriers (P staging is wave-private LDS).
// Scores computed as S = K·Q^T so C-layout has k in rows (registers) and q in
// columns (lanes): softmax row-reduction = in-lane ops + 2 shuffles.
// Per-lane online-softmax state (m,l) for its q column. O kept [q][d] C-layout.
// Block order reversed so the longest (high-q) blocks launch first.
// ---------------------------------------------------------------------------
__global__ __launch_bounds__(256) void attn_mfma(const unsigned short* __restrict__ Qbf,
                                                 const unsigned short* __restrict__ Kbf,
                                                 const unsigned short* __restrict__ Vt,
                                                 unsigned short* __restrict__ Ctx) {
    const int q0   = (gridDim.x - 1 - blockIdx.x) * 64;
    const int h    = blockIdx.y;
    const int b    = blockIdx.z;
    const int w    = threadIdx.x >> 6;
    const int lane = threadIdx.x & 63;
    const int col  = lane & 15;
    const int quad = lane >> 4;

    const int bh  = b * HQ_ + h;
    const int bkv = b * HKV_ + (h >> 2);

    const int qw   = q0 + 16 * w;      // wave's base q row
    const int myq  = qw + col;         // lane's softmax column
    const int q_hi = qw + 15;

    // Per-wave P staging: 16 q-rows x 64 k, stride 72 (b64-aligned, 2-way
    // conflicts only = free).
    __shared__ __align__(16) unsigned short sP[4][16 * 72];
    unsigned short* myP = sP[w];

    // Q B-fragments: B[k=d][n=q]: n = col, k = quad*8+j; two 32-d chunks.
    const unsigned short* qrow = Qbf + ((size_t)bh * S_ + qw + col) * HD_;
    short8 bq0 = *(const short8*)&qrow[quad * 8];
    short8 bq1 = *(const short8*)&qrow[32 + quad * 8];

    const unsigned short* Kbase = Kbf + (size_t)bkv * S_ * HD_;
    const unsigned short* Vbase = Vt + (size_t)bkv * HD_ * S_;

    floatx4 acc[4] = {};               // O[q][d]: row=q (quad*4+r), col=d
    float m_i = -1e30f, l_i = 0.f;

    const int nsteps = q_hi / 64 + 1;
    for (int it = 0; it < nsteps; ++it) {
        const int k0 = it * 64;
        // ---- S = K·Q^T: 4 tiles of 16 k-rows ----
        floatx4 sc[4];
#pragma unroll
        for (int t = 0; t < 4; ++t) {
            const unsigned short* krow =
                Kbase + (size_t)(k0 + 16 * t + col) * HD_;
            short8 ak0 = *(const short8*)&krow[quad * 8];
            short8 ak1 = *(const short8*)&krow[32 + quad * 8];
            floatx4 z = {0.f, 0.f, 0.f, 0.f};
            z = __builtin_amdgcn_mfma_f32_16x16x32_bf16(ak0, bq0, z, 0, 0, 0);
            z = __builtin_amdgcn_mfma_f32_16x16x32_bf16(ak1, bq1, z, 0, 0, 0);
            // causal mask: C row = k = k0+16t+quad*4+r, col = q = myq
#pragma unroll
            for (int r = 0; r < 4; ++r)
                if (k0 + 16 * t + quad * 4 + r > myq) z[r] = -1e30f;
            sc[t] = z;
        }
        // ---- column max: 15 in-lane + 2 shuffles ----
        float vmax = sc[0][0];
#pragma unroll
        for (int t = 0; t < 4; ++t)
#pragma unroll
            for (int r = 0; r < 4; ++r)
                vmax = fmaxf(vmax, sc[t][r]);
        vmax = fmaxf(vmax, __shfl_xor(vmax, 16, 64));
        vmax = fmaxf(vmax, __shfl_xor(vmax, 32, 64));
        const float mnew = fmaxf(m_i, vmax);
        const float alpha = __expf(m_i - mnew);
        m_i = mnew;
        // ---- exp, P -> LDS (packed b64 per tile), column sum ----
        float lsum = 0.f;
#pragma unroll
        for (int t = 0; t < 4; ++t) {
            float p0 = __expf(sc[t][0] - mnew);
            float p1 = __expf(sc[t][1] - mnew);
            float p2 = __expf(sc[t][2] - mnew);
            float p3 = __expf(sc[t][3] - mnew);
            lsum += (p0 + p1) + (p2 + p3);
            ushort4 pk = {f2bf(p0), f2bf(p1), f2bf(p2), f2bf(p3)};
            *(ushort4*)&myP[col * 72 + 16 * t + quad * 4] = pk;
        }
        lsum += __shfl_xor(lsum, 16, 64);
        lsum += __shfl_xor(lsum, 32, 64);
        l_i = l_i * alpha + lsum;
        // ---- rescale O by alpha (alpha indexed by q = row) ----
        float a_r[4];
#pragma unroll
        for (int r = 0; r < 4; ++r)
            a_r[r] = __shfl(alpha, quad * 4 + r, 64);
#pragma unroll
        for (int nt = 0; nt < 4; ++nt)
#pragma unroll
            for (int r = 0; r < 4; ++r)
                acc[nt][r] *= a_r[r];
        // ---- PV: P as A-operand (from LDS), V^T as B-operand ----
        short8 pa0 = *(const short8*)&myP[col * 72 + quad * 8];
        short8 pa1 = *(const short8*)&myP[col * 72 + 32 + quad * 8];
#pragma unroll
        for (int nt = 0; nt < 4; ++nt) {
            const unsigned short* vrow = Vbase + (size_t)(nt * 16 + col) * S_ + k0;
            short8 vb0 = *(const short8*)&vrow[quad * 8];
            short8 vb1 = *(const short8*)&vrow[32 + quad * 8];
            acc[nt] = __builtin_amdgcn_mfma_f32_16x16x32_bf16(pa0, vb0, acc[nt], 0, 0, 0);
            acc[nt] = __builtin_amdgcn_mfma_f32_16x16x32_bf16(pa1, vb1, acc[nt], 0, 0, 0);
        }
    }

    // ---- epilogue ----
    const float invl = 1.0f / l_i;
    float inv_r[4];
#pragma unroll
    for (int r = 0; r < 4; ++r)
        inv_r[r] = __shfl(invl, quad * 4 + r, 64);
#pragma unroll
    for (int nt = 0; nt < 4; ++nt)
#pragma unroll
        for (int r = 0; r < 4; ++r)
            Ctx[(size_t)(b * S_ + qw + quad * 4 + r) * HID_ + h * HD_ + nt * 16 + col] =
                f2bf(acc[nt][r] * inv_r[r]);
}

// ---------------------------------------------------------------------------
extern "C" void kernel_launch(void* const* d_in, const int* in_sizes, int n_in,
                              void* d_out, int out_size, void* d_ws, size_t ws_size,
                              hipStream_t stream) {
    const float* X    = (const float*)d_in[0];
    const float* cosT = (const float*)d_in[1];
    const float* sinT = (const float*)d_in[2];
    const float* Wq   = (const float*)d_in[3];
    const float* Wk   = (const float*)d_in[4];
    const float* Wv   = (const float*)d_in[5];
    const float* Wo   = (const float*)d_in[6];

    const int M = B_ * S_;          // 2048
    const size_t MB = 1024u * 1024u;

    // Workspace (28 MB peak), lifetime-aliased as in round 3:
    //   [0,8):   Xbf -> Qbf      [8,20): WcatT -> Kbf/Vt/Ctxbf
    //   [20,28): WoT             QKVbf (12 MB) lives in d_out.
    char* ws = (char*)d_ws;
    unsigned short* Xbf   = (unsigned short*)(ws);
    unsigned short* Qbf   = (unsigned short*)(ws);
    unsigned short* WcatT = (unsigned short*)(ws + 8 * MB);
    unsigned short* Kbf   = (unsigned short*)(ws + 8 * MB);
    unsigned short* Vt    = (unsigned short*)(ws + 10 * MB);
    unsigned short* Ctxbf = (unsigned short*)(ws + 12 * MB);
    unsigned short* WoT   = (unsigned short*)(ws + 20 * MB);
    unsigned short* QKVbf = (unsigned short*)d_out;
    float* out = (float*)d_out;

    // X -> bf16
    convert_x<<<(M * HID_ / 4) / 256, 256, 0, stream>>>(X, Xbf);

    // All weight transposes (one kernel)
    transpose_all<<<10240, 256, 0, stream>>>(Wq, Wk, Wv, Wo, WcatT, WoT);

    // Fused QKV projection (bf16 MFMA) -> bf16 QKV in d_out scratch
    gemm_mfma<true><<<dim3(NQKV / 128, M / 128), 256, 0, stream>>>(
        Xbf, WcatT, QKVbf, M, NQKV, HID_);

    // Fused RoPE + layout conversion (one kernel)
    {
        int total = B_ * S_ * HQ_ * 32 + B_ * S_ * HKV_ * 32
                  + B_ * HKV_ * HD_ * (S_ / 4);
        convert_qkv<<<total / 256, 256, 0, stream>>>(QKVbf, cosT, sinT, Qbf, Kbf, Vt);
    }

    // Flash attention (bf16 MFMA, barrier-free) -> bf16 context
    attn_mfma<<<dim3(S_ / 64, HQ_, B_), 256, 0, stream>>>(Qbf, Kbf, Vt, Ctxbf);

    // Output projection (bf16 MFMA) -> fp32 out
    gemm_mfma<false><<<dim3(HID_ / 128, M / 128), 256, 0, stream>>>(
        Ctxbf, WoT, out, M, HID_, HID_);
}

// Round 5
// 324.088 us; speedup vs baseline: 6.3046x; 1.0345x over previous
//
#include <hip/hip_runtime.h>
#include <math.h>

#define B_   2
#define S_   1024
#define HID_ 2048
#define HQ_  32
#define HKV_ 8
#define HD_  64
#define NQKV 3072   // HID + 2*HKV*HD

using short8  = __attribute__((ext_vector_type(8))) short;
using floatx4 = __attribute__((ext_vector_type(4))) float;

__device__ __forceinline__ unsigned short f2bf(float x) {
    unsigned int u = __builtin_bit_cast(unsigned int, x);
    u += 0x7FFFu + ((u >> 16) & 1u);
    return (unsigned short)(u >> 16);
}
__device__ __forceinline__ float bf2f(unsigned short u) {
    return __builtin_bit_cast(float, (unsigned int)u << 16);
}

__device__ __forceinline__ void gl_lds16(const unsigned short* g, unsigned short* l) {
    __builtin_amdgcn_global_load_lds(
        (const __attribute__((address_space(1))) void*)g,
        (__attribute__((address_space(3))) void*)l, 16, 0, 0);
}

// ---------------------------------------------------------------------------
// bf16 MFMA GEMM (unchanged): C(MxN) = A(MxK) @ Bt(NxK)^T.
// 128x128 tile, BK=32, 256 threads = 4 waves in 2x2 of 64x64 sub-tiles.
// ---------------------------------------------------------------------------
template <bool BF16OUT>
__global__ __launch_bounds__(256) void gemm_mfma(const unsigned short* __restrict__ A,
                                                 const unsigned short* __restrict__ Bt,
                                                 void* __restrict__ Cv,
                                                 int M, int N, int K) {
    __shared__ __align__(16) unsigned short As[128 * 32];
    __shared__ __align__(16) unsigned short Bs[128 * 32];

    const int tid  = threadIdx.x;
    const int w    = tid >> 6;
    const int lane = tid & 63;
    const int col  = lane & 15;
    const int quad = lane >> 4;
    const int m0 = blockIdx.y * 128;
    const int n0 = blockIdx.x * 128;
    const int wm = (w >> 1) * 64;
    const int wn = (w & 1) * 64;

    const int srow = lane >> 2;
    const int skof = (lane & 3) * 8;
    const unsigned short* Ag = A  + (size_t)(m0 + srow) * K + skof;
    const unsigned short* Bg = Bt + (size_t)(n0 + srow) * K + skof;
    const int rb = w * 16;

    floatx4 acc[4][4] = {};

    for (int k0 = 0; k0 < K; k0 += 32) {
        gl_lds16(Ag + (size_t)(rb     ) * K + k0, &As[(rb     ) * 32]);
        gl_lds16(Ag + (size_t)(rb + 64) * K + k0, &As[(rb + 64) * 32]);
        gl_lds16(Bg + (size_t)(rb     ) * K + k0, &Bs[(rb     ) * 32]);
        gl_lds16(Bg + (size_t)(rb + 64) * K + k0, &Bs[(rb + 64) * 32]);
        __syncthreads();

        short8 af[4], bfr[4];
#pragma unroll
        for (int i = 0; i < 4; ++i)
            af[i] = *(const short8*)&As[(wm + i * 16 + col) * 32 + quad * 8];
#pragma unroll
        for (int j = 0; j < 4; ++j)
            bfr[j] = *(const short8*)&Bs[(wn + j * 16 + col) * 32 + quad * 8];
#pragma unroll
        for (int i = 0; i < 4; ++i)
#pragma unroll
            for (int j = 0; j < 4; ++j)
                acc[i][j] = __builtin_amdgcn_mfma_f32_16x16x32_bf16(
                    af[i], bfr[j], acc[i][j], 0, 0, 0);
        __syncthreads();
    }

#pragma unroll
    for (int i = 0; i < 4; ++i)
#pragma unroll
        for (int j = 0; j < 4; ++j)
#pragma unroll
            for (int r = 0; r < 4; ++r) {
                size_t off = (size_t)(m0 + wm + i * 16 + quad * 4 + r) * N
                           + (n0 + wn + j * 16 + col);
                if constexpr (BF16OUT)
                    ((unsigned short*)Cv)[off] = f2bf(acc[i][j][r]);
                else
                    ((float*)Cv)[off] = acc[i][j][r];
            }
}

// ---------------------------------------------------------------------------
// fp32 -> bf16 elementwise (X)
// ---------------------------------------------------------------------------
__global__ __launch_bounds__(256) void convert_x(const float* __restrict__ in,
                                                 unsigned short* __restrict__ out) {
    int tid = blockIdx.x * 256 + threadIdx.x;
    float4 v = *(const float4*)&in[(size_t)tid * 4];
    ushort4 o = {f2bf(v.x), f2bf(v.y), f2bf(v.z), f2bf(v.w)};
    *(ushort4*)&out[(size_t)tid * 4] = o;
}

// ---------------------------------------------------------------------------
// All 4 weight transposes in ONE kernel (fp32 KxN -> bf16 NxK), 32x32 tiles.
// ---------------------------------------------------------------------------
__global__ __launch_bounds__(256) void transpose_all(const float* __restrict__ Wq,
                                                     const float* __restrict__ Wk,
                                                     const float* __restrict__ Wv,
                                                     const float* __restrict__ Wo,
                                                     unsigned short* __restrict__ WcatT,
                                                     unsigned short* __restrict__ WoT) {
    __shared__ float tile[32][33];
    int bid = blockIdx.x;
    const float* W;
    unsigned short* WT;
    int N, tn0, tk0;
    if (bid < 4096) {
        W = Wq; WT = WcatT; N = HID_;
        tn0 = (bid & 63) * 32; tk0 = (bid >> 6) * 32;
    } else if (bid < 5120) {
        bid -= 4096;
        W = Wk; WT = WcatT + (size_t)HID_ * HID_; N = 512;
        tn0 = (bid & 15) * 32; tk0 = (bid >> 4) * 32;
    } else if (bid < 6144) {
        bid -= 5120;
        W = Wv; WT = WcatT + (size_t)(HID_ + 512) * HID_; N = 512;
        tn0 = (bid & 15) * 32; tk0 = (bid >> 4) * 32;
    } else {
        bid -= 6144;
        W = Wo; WT = WoT; N = HID_;
        tn0 = (bid & 63) * 32; tk0 = (bid >> 6) * 32;
    }
    const int r  = threadIdx.x >> 3;
    const int c4 = (threadIdx.x & 7) * 4;
    float4 v = *(const float4*)&W[(size_t)(tk0 + r) * N + tn0 + c4];
    tile[r][c4 + 0] = v.x;
    tile[r][c4 + 1] = v.y;
    tile[r][c4 + 2] = v.z;
    tile[r][c4 + 3] = v.w;
    __syncthreads();
    ushort4 o = {f2bf(tile[c4 + 0][r]), f2bf(tile[c4 + 1][r]),
                 f2bf(tile[c4 + 2][r]), f2bf(tile[c4 + 3][r])};
    *(ushort4*)&WT[(size_t)(tn0 + r) * HID_ + tk0 + c4] = o;
}

// ---------------------------------------------------------------------------
// Fused RoPE + layout conversion, all three outputs in ONE kernel.
// ---------------------------------------------------------------------------
__global__ __launch_bounds__(256) void convert_qkv(const unsigned short* __restrict__ QKV,
                                                   const float* __restrict__ cosT,
                                                   const float* __restrict__ sinT,
                                                   unsigned short* __restrict__ Qbf,
                                                   unsigned short* __restrict__ Kbf,
                                                   unsigned short* __restrict__ Vt) {
    int tid = blockIdx.x * 256 + threadIdx.x;
    const int NQ = B_ * S_ * HQ_ * 32;
    const int NK = B_ * S_ * HKV_ * 32;
    if (tid < NQ) {
        int d = tid & 31;
        int h = (tid >> 5) & (HQ_ - 1);
        int s = (tid >> 10) & (S_ - 1);
        int b = tid >> 20;
        const unsigned short* row = QKV + (size_t)(b * S_ + s) * NQKV + h * HD_;
        float x0 = bf2f(row[d]), x1 = bf2f(row[d + 32]);
        float c0 = cosT[s * HD_ + d],      s0 = sinT[s * HD_ + d];
        float c1 = cosT[s * HD_ + d + 32], s1 = sinT[s * HD_ + d + 32];
        unsigned short* orow = Qbf + ((size_t)(b * HQ_ + h) * S_ + s) * HD_;
        orow[d]      = f2bf((x0 * c0 - x1 * s0) * 0.125f);
        orow[d + 32] = f2bf((x1 * c1 + x0 * s1) * 0.125f);
    } else if (tid < NQ + NK) {
        tid -= NQ;
        int d  = tid & 31;
        int kv = (tid >> 5) & (HKV_ - 1);
        int s  = (tid >> 8) & (S_ - 1);
        int b  = tid >> 18;
        const unsigned short* row = QKV + (size_t)(b * S_ + s) * NQKV + HID_ + kv * HD_;
        float x0 = bf2f(row[d]), x1 = bf2f(row[d + 32]);
        float c0 = cosT[s * HD_ + d],      s0 = sinT[s * HD_ + d];
        float c1 = cosT[s * HD_ + d + 32], s1 = sinT[s * HD_ + d + 32];
        unsigned short* orow = Kbf + ((size_t)(b * HKV_ + kv) * S_ + s) * HD_;
        orow[d]      = f2bf(x0 * c0 - x1 * s0);
        orow[d + 32] = f2bf(x1 * c1 + x0 * s1);
    } else {
        tid -= NQ + NK;
        int s4 = tid & 255;
        int d  = (tid >> 8) & (HD_ - 1);
        int kv = (tid >> 14) & (HKV_ - 1);
        int b  = tid >> 17;
        int s  = s4 * 4;
        const unsigned short* base =
            QKV + (size_t)b * S_ * NQKV + HID_ + 512 + kv * HD_ + d;
        ushort4 o;
        o.x = base[(size_t)(s + 0) * NQKV];
        o.y = base[(size_t)(s + 1) * NQKV];
        o.z = base[(size_t)(s + 2) * NQKV];
        o.w = base[(size_t)(s + 3) * NQKV];
        *(ushort4*)&Vt[((size_t)(b * HKV_ + kv) * HD_ + d) * S_ + s] = o;
    }
}

// ---------------------------------------------------------------------------
// Flash attention with SPLIT-K (flash-decode). KQ^T orientation as round 4.
// Per (b,h): 24 chunks (blockIdx.x = c):
//   c in [0,8):   q-tile 8+c,  keys [0,512)          -> partial (part 0)
//   c in [8,16):  q-tile 15-c, keys [0, causal end)  -> direct write (q-tiles 0..7)
//   c in [16,24): q-tile 31-c, keys [512, causal end)-> partial (part 1)
// Max 8 steps per block (was 16); 1536 blocks (was 1024) for occupancy.
// Partials: unnormalized O (bf16) + m,l (fp32), indexed
//   pidx = ((b*HQ+h)*8 + qtile-8)*2 + part.
// ---------------------------------------------------------------------------
__global__ __launch_bounds__(256) void attn_mfma(const unsigned short* __restrict__ Qbf,
                                                 const unsigned short* __restrict__ Kbf,
                                                 const unsigned short* __restrict__ Vt,
                                                 unsigned short* __restrict__ Ctx,
                                                 unsigned short* __restrict__ Opart,
                                                 float* __restrict__ Mpart,
                                                 float* __restrict__ Lpart) {
    const int c = blockIdx.x;
    const int h = blockIdx.y;
    const int b = blockIdx.z;

    int qtile, klo, part;
    bool partial;
    if (c < 8)       { qtile = 8 + c;  klo = 0;   partial = true;  part = 0; }
    else if (c < 16) { qtile = 15 - c; klo = 0;   partial = false; part = 0; }
    else             { qtile = 31 - c; klo = 512; partial = true;  part = 1; }

    const int q0   = qtile * 64;
    const int w    = threadIdx.x >> 6;
    const int lane = threadIdx.x & 63;
    const int col  = lane & 15;
    const int quad = lane >> 4;

    const int bh  = b * HQ_ + h;
    const int bkv = b * HKV_ + (h >> 2);

    const int qw   = q0 + 16 * w;
    const int myq  = qw + col;
    const int q_hi = qw + 15;

    __shared__ __align__(16) unsigned short sP[4][16 * 72];
    unsigned short* myP = sP[w];

    const unsigned short* qrow = Qbf + ((size_t)bh * S_ + qw + col) * HD_;
    short8 bq0 = *(const short8*)&qrow[quad * 8];
    short8 bq1 = *(const short8*)&qrow[32 + quad * 8];

    const unsigned short* Kbase = Kbf + (size_t)bkv * S_ * HD_;
    const unsigned short* Vbase = Vt + (size_t)bkv * HD_ * S_;

    floatx4 acc[4] = {};
    float m_i = -1e30f, l_i = 0.f;

    const int kmax   = (partial && part == 0) ? 512 : (q_hi + 1);
    const int nsteps = (kmax - klo + 63) >> 6;

    for (int it = 0; it < nsteps; ++it) {
        const int k0 = klo + it * 64;
        floatx4 sc[4];
#pragma unroll
        for (int t = 0; t < 4; ++t) {
            const unsigned short* krow =
                Kbase + (size_t)(k0 + 16 * t + col) * HD_;
            short8 ak0 = *(const short8*)&krow[quad * 8];
            short8 ak1 = *(const short8*)&krow[32 + quad * 8];
            floatx4 z = {0.f, 0.f, 0.f, 0.f};
            z = __builtin_amdgcn_mfma_f32_16x16x32_bf16(ak0, bq0, z, 0, 0, 0);
            z = __builtin_amdgcn_mfma_f32_16x16x32_bf16(ak1, bq1, z, 0, 0, 0);
#pragma unroll
            for (int r = 0; r < 4; ++r)
                if (k0 + 16 * t + quad * 4 + r > myq) z[r] = -1e30f;
            sc[t] = z;
        }
        float vmax = sc[0][0];
#pragma unroll
        for (int t = 0; t < 4; ++t)
#pragma unroll
            for (int r = 0; r < 4; ++r)
                vmax = fmaxf(vmax, sc[t][r]);
        vmax = fmaxf(vmax, __shfl_xor(vmax, 16, 64));
        vmax = fmaxf(vmax, __shfl_xor(vmax, 32, 64));
        const float mnew = fmaxf(m_i, vmax);
        const float alpha = __expf(m_i - mnew);
        m_i = mnew;
        float lsum = 0.f;
#pragma unroll
        for (int t = 0; t < 4; ++t) {
            float p0 = __expf(sc[t][0] - mnew);
            float p1 = __expf(sc[t][1] - mnew);
            float p2 = __expf(sc[t][2] - mnew);
            float p3 = __expf(sc[t][3] - mnew);
            lsum += (p0 + p1) + (p2 + p3);
            ushort4 pk = {f2bf(p0), f2bf(p1), f2bf(p2), f2bf(p3)};
            *(ushort4*)&myP[col * 72 + 16 * t + quad * 4] = pk;
        }
        lsum += __shfl_xor(lsum, 16, 64);
        lsum += __shfl_xor(lsum, 32, 64);
        l_i = l_i * alpha + lsum;
        float a_r[4];
#pragma unroll
        for (int r = 0; r < 4; ++r)
            a_r[r] = __shfl(alpha, quad * 4 + r, 64);
#pragma unroll
        for (int nt = 0; nt < 4; ++nt)
#pragma unroll
            for (int r = 0; r < 4; ++r)
                acc[nt][r] *= a_r[r];
        short8 pa0 = *(const short8*)&myP[col * 72 + quad * 8];
        short8 pa1 = *(const short8*)&myP[col * 72 + 32 + quad * 8];
#pragma unroll
        for (int nt = 0; nt < 4; ++nt) {
            const unsigned short* vrow = Vbase + (size_t)(nt * 16 + col) * S_ + k0;
            short8 vb0 = *(const short8*)&vrow[quad * 8];
            short8 vb1 = *(const short8*)&vrow[32 + quad * 8];
            acc[nt] = __builtin_amdgcn_mfma_f32_16x16x32_bf16(pa0, vb0, acc[nt], 0, 0, 0);
            acc[nt] = __builtin_amdgcn_mfma_f32_16x16x32_bf16(pa1, vb1, acc[nt], 0, 0, 0);
        }
    }

    if (!partial) {
        const float invl = 1.0f / l_i;
        float inv_r[4];
#pragma unroll
        for (int r = 0; r < 4; ++r)
            inv_r[r] = __shfl(invl, quad * 4 + r, 64);
#pragma unroll
        for (int nt = 0; nt < 4; ++nt)
#pragma unroll
            for (int r = 0; r < 4; ++r)
                Ctx[(size_t)(b * S_ + qw + quad * 4 + r) * HID_ + h * HD_ + nt * 16 + col] =
                    f2bf(acc[nt][r] * inv_r[r]);
    } else {
        const int pidx = (bh * 8 + (qtile - 8)) * 2 + part;
        unsigned short* Po = Opart + (size_t)pidx * 64 * 64;
#pragma unroll
        for (int nt = 0; nt < 4; ++nt)
#pragma unroll
            for (int r = 0; r < 4; ++r)
                Po[(16 * w + quad * 4 + r) * 64 + nt * 16 + col] = f2bf(acc[nt][r]);
        if (quad == 0) {
            Mpart[pidx * 64 + 16 * w + col] = m_i;
            Lpart[pidx * 64 + 16 * w + col] = l_i;
        }
    }
}

// ---------------------------------------------------------------------------
// Combine the two partials of each split q-tile (q-tiles 8..15 per (b,h)).
// Grid 512 blocks: bid -> (bh, qtile-8). Thread: q = tid>>2, d0 = (tid&3)*16.
// ---------------------------------------------------------------------------
__global__ __launch_bounds__(256) void attn_combine(const unsigned short* __restrict__ Opart,
                                                    const float* __restrict__ Mpart,
                                                    const float* __restrict__ Lpart,
                                                    unsigned short* __restrict__ Ctx) {
    const int bid = blockIdx.x;
    const int bh  = bid >> 3;
    const int qt8 = bid & 7;
    const int b   = bh >> 5;        // HQ_=32
    const int h   = bh & 31;
    const int tid = threadIdx.x;
    const int q   = tid >> 2;
    const int d0  = (tid & 3) << 4;

    const int p0 = (bh * 8 + qt8) * 2;
    const int p1 = p0 + 1;
    float m1 = Mpart[p0 * 64 + q], m2 = Mpart[p1 * 64 + q];
    float l1 = Lpart[p0 * 64 + q], l2 = Lpart[p1 * 64 + q];
    float m  = fmaxf(m1, m2);
    float w1 = __expf(m1 - m), w2 = __expf(m2 - m);
    float rinv = 1.0f / (w1 * l1 + w2 * l2);

    const unsigned short* O1 = Opart + ((size_t)p0 * 64 + q) * 64 + d0;
    const unsigned short* O2 = Opart + ((size_t)p1 * 64 + q) * 64 + d0;
    unsigned short* dst =
        Ctx + (size_t)(b * S_ + (qt8 + 8) * 64 + q) * HID_ + h * HD_ + d0;

    short8 a0 = *(const short8*)&O1[0], a1 = *(const short8*)&O1[8];
    short8 b0 = *(const short8*)&O2[0], b1 = *(const short8*)&O2[8];
    short8 o0, o1;
#pragma unroll
    for (int i = 0; i < 8; ++i) {
        o0[i] = (short)f2bf((w1 * bf2f((unsigned short)a0[i]) +
                             w2 * bf2f((unsigned short)b0[i])) * rinv);
        o1[i] = (short)f2bf((w1 * bf2f((unsigned short)a1[i]) +
                             w2 * bf2f((unsigned short)b1[i])) * rinv);
    }
    *(short8*)&dst[0] = o0;
    *(short8*)&dst[8] = o1;
}

// ---------------------------------------------------------------------------
extern "C" void kernel_launch(void* const* d_in, const int* in_sizes, int n_in,
                              void* d_out, int out_size, void* d_ws, size_t ws_size,
                              hipStream_t stream) {
    const float* X    = (const float*)d_in[0];
    const float* cosT = (const float*)d_in[1];
    const float* sinT = (const float*)d_in[2];
    const float* Wq   = (const float*)d_in[3];
    const float* Wk   = (const float*)d_in[4];
    const float* Wv   = (const float*)d_in[5];
    const float* Wo   = (const float*)d_in[6];

    const int M = B_ * S_;          // 2048
    const size_t MB = 1024u * 1024u;

    // Workspace (28 MB), lifetime-aliased:
    //   [0,8):   Xbf -> Qbf      [8,10): Kbf   [10,12): Vt
    //   [12,20): Ctxbf           [20,28): WoT
    //   d_out (16 MB): QKVbf (12 MB, dead after convert_qkv) -> attention
    //   partials: Opart bf16 8 MB @0, Mpart/Lpart fp32 @8 MB; then final GEMM
    //   overwrites d_out with the fp32 result.
    char* ws = (char*)d_ws;
    unsigned short* Xbf   = (unsigned short*)(ws);
    unsigned short* Qbf   = (unsigned short*)(ws);
    unsigned short* WcatT = (unsigned short*)(ws + 8 * MB);
    unsigned short* Kbf   = (unsigned short*)(ws + 8 * MB);
    unsigned short* Vt    = (unsigned short*)(ws + 10 * MB);
    unsigned short* Ctxbf = (unsigned short*)(ws + 12 * MB);
    unsigned short* WoT   = (unsigned short*)(ws + 20 * MB);
    unsigned short* QKVbf = (unsigned short*)d_out;
    unsigned short* Opart = (unsigned short*)d_out;
    float* Mpart = (float*)((char*)d_out + 8 * MB);
    float* Lpart = (float*)((char*)d_out + 8 * MB + 256 * 1024);
    float* out = (float*)d_out;

    // X -> bf16
    convert_x<<<(M * HID_ / 4) / 256, 256, 0, stream>>>(X, Xbf);

    // All weight transposes (one kernel)
    transpose_all<<<10240, 256, 0, stream>>>(Wq, Wk, Wv, Wo, WcatT, WoT);

    // Fused QKV projection (bf16 MFMA) -> bf16 QKV in d_out scratch
    gemm_mfma<true><<<dim3(NQKV / 128, M / 128), 256, 0, stream>>>(
        Xbf, WcatT, QKVbf, M, NQKV, HID_);

    // Fused RoPE + layout conversion (one kernel)
    {
        int total = B_ * S_ * HQ_ * 32 + B_ * S_ * HKV_ * 32
                  + B_ * HKV_ * HD_ * (S_ / 4);
        convert_qkv<<<total / 256, 256, 0, stream>>>(QKVbf, cosT, sinT, Qbf, Kbf, Vt);
    }

    // Flash attention, split-K (24 chunks per (b,h))
    attn_mfma<<<dim3(24, HQ_, B_), 256, 0, stream>>>(
        Qbf, Kbf, Vt, Ctxbf, Opart, Mpart, Lpart);

    // Merge split partials into Ctxbf
    attn_combine<<<512, 256, 0, stream>>>(Opart, Mpart, Lpart, Ctxbf);

    // Output projection (bf16 MFMA) -> fp32 out
    gemm_mfma<false><<<dim3(HID_ / 128, M / 128), 256, 0, stream>>>(
        Ctxbf, WoT, out, M, HID_, HID_);
}

// Round 6
// 314.831 us; speedup vs baseline: 6.4900x; 1.0294x over previous
//
#include <hip/hip_runtime.h>
#include <math.h>

#define B_   2
#define S_   1024
#define HID_ 2048
#define HQ_  32
#define HKV_ 8
#define HD_  64
#define NQKV 3072   // HID + 2*HKV*HD

using short8  = __attribute__((ext_vector_type(8))) short;
using floatx4 = __attribute__((ext_vector_type(4))) float;

__device__ __forceinline__ unsigned short f2bf(float x) {
    unsigned int u = __builtin_bit_cast(unsigned int, x);
    u += 0x7FFFu + ((u >> 16) & 1u);
    return (unsigned short)(u >> 16);
}
__device__ __forceinline__ float bf2f(unsigned short u) {
    return __builtin_bit_cast(float, (unsigned int)u << 16);
}

__device__ __forceinline__ void gl_lds16(const unsigned short* g, unsigned short* l) {
    __builtin_amdgcn_global_load_lds(
        (const __attribute__((address_space(1))) void*)g,
        (__attribute__((address_space(3))) void*)l, 16, 0, 0);
}

// ---------------------------------------------------------------------------
// bf16 MFMA GEMM (unchanged): C(MxN) = A(MxK) @ Bt(NxK)^T.
// ---------------------------------------------------------------------------
template <bool BF16OUT>
__global__ __launch_bounds__(256) void gemm_mfma(const unsigned short* __restrict__ A,
                                                 const unsigned short* __restrict__ Bt,
                                                 void* __restrict__ Cv,
                                                 int M, int N, int K) {
    __shared__ __align__(16) unsigned short As[128 * 32];
    __shared__ __align__(16) unsigned short Bs[128 * 32];

    const int tid  = threadIdx.x;
    const int w    = tid >> 6;
    const int lane = tid & 63;
    const int col  = lane & 15;
    const int quad = lane >> 4;
    const int m0 = blockIdx.y * 128;
    const int n0 = blockIdx.x * 128;
    const int wm = (w >> 1) * 64;
    const int wn = (w & 1) * 64;

    const int srow = lane >> 2;
    const int skof = (lane & 3) * 8;
    const unsigned short* Ag = A  + (size_t)(m0 + srow) * K + skof;
    const unsigned short* Bg = Bt + (size_t)(n0 + srow) * K + skof;
    const int rb = w * 16;

    floatx4 acc[4][4] = {};

    for (int k0 = 0; k0 < K; k0 += 32) {
        gl_lds16(Ag + (size_t)(rb     ) * K + k0, &As[(rb     ) * 32]);
        gl_lds16(Ag + (size_t)(rb + 64) * K + k0, &As[(rb + 64) * 32]);
        gl_lds16(Bg + (size_t)(rb     ) * K + k0, &Bs[(rb     ) * 32]);
        gl_lds16(Bg + (size_t)(rb + 64) * K + k0, &Bs[(rb + 64) * 32]);
        __syncthreads();

        short8 af[4], bfr[4];
#pragma unroll
        for (int i = 0; i < 4; ++i)
            af[i] = *(const short8*)&As[(wm + i * 16 + col) * 32 + quad * 8];
#pragma unroll
        for (int j = 0; j < 4; ++j)
            bfr[j] = *(const short8*)&Bs[(wn + j * 16 + col) * 32 + quad * 8];
#pragma unroll
        for (int i = 0; i < 4; ++i)
#pragma unroll
            for (int j = 0; j < 4; ++j)
                acc[i][j] = __builtin_amdgcn_mfma_f32_16x16x32_bf16(
                    af[i], bfr[j], acc[i][j], 0, 0, 0);
        __syncthreads();
    }

#pragma unroll
    for (int i = 0; i < 4; ++i)
#pragma unroll
        for (int j = 0; j < 4; ++j)
#pragma unroll
            for (int r = 0; r < 4; ++r) {
                size_t off = (size_t)(m0 + wm + i * 16 + quad * 4 + r) * N
                           + (n0 + wn + j * 16 + col);
                if constexpr (BF16OUT)
                    ((unsigned short*)Cv)[off] = f2bf(acc[i][j][r]);
                else
                    ((float*)Cv)[off] = acc[i][j][r];
            }
}

// ---------------------------------------------------------------------------
// fp32 -> bf16 elementwise (X)
// ---------------------------------------------------------------------------
__global__ __launch_bounds__(256) void convert_x(const float* __restrict__ in,
                                                 unsigned short* __restrict__ out) {
    int tid = blockIdx.x * 256 + threadIdx.x;
    float4 v = *(const float4*)&in[(size_t)tid * 4];
    ushort4 o = {f2bf(v.x), f2bf(v.y), f2bf(v.z), f2bf(v.w)};
    *(ushort4*)&out[(size_t)tid * 4] = o;
}

// ---------------------------------------------------------------------------
// All 4 weight transposes in ONE kernel (fp32 KxN -> bf16 NxK), 32x32 tiles.
// ---------------------------------------------------------------------------
__global__ __launch_bounds__(256) void transpose_all(const float* __restrict__ Wq,
                                                     const float* __restrict__ Wk,
                                                     const float* __restrict__ Wv,
                                                     const float* __restrict__ Wo,
                                                     unsigned short* __restrict__ WcatT,
                                                     unsigned short* __restrict__ WoT) {
    __shared__ float tile[32][33];
    int bid = blockIdx.x;
    const float* W;
    unsigned short* WT;
    int N, tn0, tk0;
    if (bid < 4096) {
        W = Wq; WT = WcatT; N = HID_;
        tn0 = (bid & 63) * 32; tk0 = (bid >> 6) * 32;
    } else if (bid < 5120) {
        bid -= 4096;
        W = Wk; WT = WcatT + (size_t)HID_ * HID_; N = 512;
        tn0 = (bid & 15) * 32; tk0 = (bid >> 4) * 32;
    } else if (bid < 6144) {
        bid -= 5120;
        W = Wv; WT = WcatT + (size_t)(HID_ + 512) * HID_; N = 512;
        tn0 = (bid & 15) * 32; tk0 = (bid >> 4) * 32;
    } else {
        bid -= 6144;
        W = Wo; WT = WoT; N = HID_;
        tn0 = (bid & 63) * 32; tk0 = (bid >> 6) * 32;
    }
    const int r  = threadIdx.x >> 3;
    const int c4 = (threadIdx.x & 7) * 4;
    float4 v = *(const float4*)&W[(size_t)(tk0 + r) * N + tn0 + c4];
    tile[r][c4 + 0] = v.x;
    tile[r][c4 + 1] = v.y;
    tile[r][c4 + 2] = v.z;
    tile[r][c4 + 3] = v.w;
    __syncthreads();
    ushort4 o = {f2bf(tile[c4 + 0][r]), f2bf(tile[c4 + 1][r]),
                 f2bf(tile[c4 + 2][r]), f2bf(tile[c4 + 3][r])};
    *(ushort4*)&WT[(size_t)(tn0 + r) * HID_ + tk0 + c4] = o;
}

// ---------------------------------------------------------------------------
// Fused RoPE + layout conversion, all three outputs in ONE kernel.
// ---------------------------------------------------------------------------
__global__ __launch_bounds__(256) void convert_qkv(const unsigned short* __restrict__ QKV,
                                                   const float* __restrict__ cosT,
                                                   const float* __restrict__ sinT,
                                                   unsigned short* __restrict__ Qbf,
                                                   unsigned short* __restrict__ Kbf,
                                                   unsigned short* __restrict__ Vt) {
    int tid = blockIdx.x * 256 + threadIdx.x;
    const int NQ = B_ * S_ * HQ_ * 32;
    const int NK = B_ * S_ * HKV_ * 32;
    if (tid < NQ) {
        int d = tid & 31;
        int h = (tid >> 5) & (HQ_ - 1);
        int s = (tid >> 10) & (S_ - 1);
        int b = tid >> 20;
        const unsigned short* row = QKV + (size_t)(b * S_ + s) * NQKV + h * HD_;
        float x0 = bf2f(row[d]), x1 = bf2f(row[d + 32]);
        float c0 = cosT[s * HD_ + d],      s0 = sinT[s * HD_ + d];
        float c1 = cosT[s * HD_ + d + 32], s1 = sinT[s * HD_ + d + 32];
        unsigned short* orow = Qbf + ((size_t)(b * HQ_ + h) * S_ + s) * HD_;
        orow[d]      = f2bf((x0 * c0 - x1 * s0) * 0.125f);
        orow[d + 32] = f2bf((x1 * c1 + x0 * s1) * 0.125f);
    } else if (tid < NQ + NK) {
        tid -= NQ;
        int d  = tid & 31;
        int kv = (tid >> 5) & (HKV_ - 1);
        int s  = (tid >> 8) & (S_ - 1);
        int b  = tid >> 18;
        const unsigned short* row = QKV + (size_t)(b * S_ + s) * NQKV + HID_ + kv * HD_;
        float x0 = bf2f(row[d]), x1 = bf2f(row[d + 32]);
        float c0 = cosT[s * HD_ + d],      s0 = sinT[s * HD_ + d];
        float c1 = cosT[s * HD_ + d + 32], s1 = sinT[s * HD_ + d + 32];
        unsigned short* orow = Kbf + ((size_t)(b * HKV_ + kv) * S_ + s) * HD_;
        orow[d]      = f2bf(x0 * c0 - x1 * s0);
        orow[d + 32] = f2bf(x1 * c1 + x0 * s1);
    } else {
        tid -= NQ + NK;
        int s4 = tid & 255;
        int d  = (tid >> 8) & (HD_ - 1);
        int kv = (tid >> 14) & (HKV_ - 1);
        int b  = tid >> 17;
        int s  = s4 * 4;
        const unsigned short* base =
            QKV + (size_t)b * S_ * NQKV + HID_ + 512 + kv * HD_ + d;
        ushort4 o;
        o.x = base[(size_t)(s + 0) * NQKV];
        o.y = base[(size_t)(s + 1) * NQKV];
        o.z = base[(size_t)(s + 2) * NQKV];
        o.w = base[(size_t)(s + 3) * NQKV];
        *(ushort4*)&Vt[((size_t)(b * HKV_ + kv) * HD_ + d) * S_ + s] = o;
    }
}

// ---------------------------------------------------------------------------
// Flash attention: ONE WAVE per block, 16 q-rows per wave, software-pipelined.
// Grid (96, HQ, B). Chunk map (longest work dispatched first):
//   c in [0,32):  t = 32+c, keys [0,512)        -> partial slot (t-32)*2   (8 steps)
//   c in [32,64): t = 95-c, keys [512, 16t+16)  -> partial slot (t-32)*2+1 (1..8)
//   c in [64,96): t = 95-c (0..31), keys [0, 16t+16) -> direct write        (1..8)
// Pipeline: per step issue next-step K loads + this-step V loads up front;
// QK consumes registers loaded last step; softmax hides V latency.
// Causal mask applied only when k0+63 > qw (wave-uniform branch).
// ---------------------------------------------------------------------------
__global__ __launch_bounds__(64) void attn_mfma(const unsigned short* __restrict__ Qbf,
                                                const unsigned short* __restrict__ Kbf,
                                                const unsigned short* __restrict__ Vt,
                                                unsigned short* __restrict__ Ctx,
                                                unsigned short* __restrict__ Opart,
                                                float* __restrict__ Mpart,
                                                float* __restrict__ Lpart) {
    const int c = blockIdx.x;
    const int h = blockIdx.y;
    const int b = blockIdx.z;

    int t, klo, kend, slot;
    bool partial;
    if (c < 32)      { t = 32 + c; klo = 0;   kend = 512;         partial = true;  slot = (t - 32) * 2; }
    else if (c < 64) { t = 95 - c; klo = 512; kend = 16 * t + 16; partial = true;  slot = (t - 32) * 2 + 1; }
    else             { t = 95 - c; klo = 0;   kend = 16 * t + 16; partial = false; slot = 0; }

    const int lane = threadIdx.x;
    const int col  = lane & 15;
    const int quad = lane >> 4;
    const int bh   = b * HQ_ + h;
    const int bkv  = b * HKV_ + (h >> 2);
    const int qw   = 16 * t;
    const int myq  = qw + col;

    __shared__ __align__(16) unsigned short sP[16 * 72];

    const unsigned short* qrow = Qbf + ((size_t)bh * S_ + qw + col) * HD_;
    short8 bq0 = *(const short8*)&qrow[quad * 8];
    short8 bq1 = *(const short8*)&qrow[32 + quad * 8];

    // lane-resolved base pointers
    const unsigned short* Kbase =
        Kbf + (size_t)bkv * S_ * HD_ + (size_t)col * HD_ + quad * 8;
    const unsigned short* Vbase =
        Vt + (size_t)bkv * HD_ * S_ + (size_t)col * S_ + quad * 8;

    floatx4 acc[4] = {};
    float m_i = -1e30f, l_i = 0.f;
    const int nsteps = (kend - klo + 63) >> 6;

    // prologue: K for step 0
    short8 kc[8];
#pragma unroll
    for (int tt = 0; tt < 4; ++tt) {
        const unsigned short* kp = Kbase + (size_t)(klo + 16 * tt) * HD_;
        kc[2 * tt]     = *(const short8*)kp;
        kc[2 * tt + 1] = *(const short8*)(kp + 32);
    }

    for (int it = 0; it < nsteps; ++it) {
        const int k0  = klo + it * 64;
        const int kn0 = (it + 1 < nsteps) ? k0 + 64 : k0;
        // issue next-step K and this-step V loads (consumed much later)
        short8 kn[8], vc[8];
#pragma unroll
        for (int tt = 0; tt < 4; ++tt) {
            const unsigned short* kp = Kbase + (size_t)(kn0 + 16 * tt) * HD_;
            kn[2 * tt]     = *(const short8*)kp;
            kn[2 * tt + 1] = *(const short8*)(kp + 32);
        }
#pragma unroll
        for (int nt = 0; nt < 4; ++nt) {
            const unsigned short* vp = Vbase + (size_t)(nt * 16) * S_ + k0;
            vc[2 * nt]     = *(const short8*)vp;
            vc[2 * nt + 1] = *(const short8*)(vp + 32);
        }
        // ---- S = K·Q^T from current-step registers ----
        floatx4 sc[4];
#pragma unroll
        for (int tt = 0; tt < 4; ++tt) {
            floatx4 z = {0.f, 0.f, 0.f, 0.f};
            z = __builtin_amdgcn_mfma_f32_16x16x32_bf16(kc[2 * tt],     bq0, z, 0, 0, 0);
            z = __builtin_amdgcn_mfma_f32_16x16x32_bf16(kc[2 * tt + 1], bq1, z, 0, 0, 0);
            sc[tt] = z;
        }
        if (k0 + 63 > qw) {   // wave-uniform: mask only near the diagonal
#pragma unroll
            for (int tt = 0; tt < 4; ++tt)
#pragma unroll
                for (int r = 0; r < 4; ++r)
                    if (k0 + 16 * tt + quad * 4 + r > myq) sc[tt][r] = -1e30f;
        }
        // ---- online softmax: 15 in-lane + 2 cross-quad shuffles ----
        float vmax = sc[0][0];
#pragma unroll
        for (int tt = 0; tt < 4; ++tt)
#pragma unroll
            for (int r = 0; r < 4; ++r)
                vmax = fmaxf(vmax, sc[tt][r]);
        vmax = fmaxf(vmax, __shfl_xor(vmax, 16, 64));
        vmax = fmaxf(vmax, __shfl_xor(vmax, 32, 64));
        const float mnew  = fmaxf(m_i, vmax);
        const float alpha = __expf(m_i - mnew);
        m_i = mnew;
        float lsum = 0.f;
#pragma unroll
        for (int tt = 0; tt < 4; ++tt) {
            float p0 = __expf(sc[tt][0] - mnew);
            float p1 = __expf(sc[tt][1] - mnew);
            float p2 = __expf(sc[tt][2] - mnew);
            float p3 = __expf(sc[tt][3] - mnew);
            lsum += (p0 + p1) + (p2 + p3);
            ushort4 pk = {f2bf(p0), f2bf(p1), f2bf(p2), f2bf(p3)};
            *(ushort4*)&sP[col * 72 + 16 * tt + quad * 4] = pk;
        }
        lsum += __shfl_xor(lsum, 16, 64);
        lsum += __shfl_xor(lsum, 32, 64);
        l_i = l_i * alpha + lsum;
        float a_r[4];
#pragma unroll
        for (int r = 0; r < 4; ++r)
            a_r[r] = __shfl(alpha, quad * 4 + r, 64);
#pragma unroll
        for (int nt = 0; nt < 4; ++nt)
#pragma unroll
            for (int r = 0; r < 4; ++r)
                acc[nt][r] *= a_r[r];
        // ---- PV from prefetched V registers ----
        short8 pa0 = *(const short8*)&sP[col * 72 + quad * 8];
        short8 pa1 = *(const short8*)&sP[col * 72 + 32 + quad * 8];
#pragma unroll
        for (int nt = 0; nt < 4; ++nt) {
            acc[nt] = __builtin_amdgcn_mfma_f32_16x16x32_bf16(pa0, vc[2 * nt],     acc[nt], 0, 0, 0);
            acc[nt] = __builtin_amdgcn_mfma_f32_16x16x32_bf16(pa1, vc[2 * nt + 1], acc[nt], 0, 0, 0);
        }
        // rotate pipeline
#pragma unroll
        for (int i = 0; i < 8; ++i) kc[i] = kn[i];
    }

    if (!partial) {
        const float invl = 1.0f / l_i;
        float inv_r[4];
#pragma unroll
        for (int r = 0; r < 4; ++r)
            inv_r[r] = __shfl(invl, quad * 4 + r, 64);
#pragma unroll
        for (int nt = 0; nt < 4; ++nt)
#pragma unroll
            for (int r = 0; r < 4; ++r)
                Ctx[(size_t)(b * S_ + qw + quad * 4 + r) * HID_ + h * HD_ + nt * 16 + col] =
                    f2bf(acc[nt][r] * inv_r[r]);
    } else {
        const int pidx = bh * 64 + slot;
        unsigned short* Po = Opart + (size_t)pidx * 1024;   // 16 q x 64 d
#pragma unroll
        for (int nt = 0; nt < 4; ++nt)
#pragma unroll
            for (int r = 0; r < 4; ++r)
                Po[(quad * 4 + r) * 64 + nt * 16 + col] = f2bf(acc[nt][r]);
        if (quad == 0) {
            Mpart[pidx * 16 + col] = m_i;
            Lpart[pidx * 16 + col] = l_i;
        }
    }
}

// ---------------------------------------------------------------------------
// Merge the two partials of tiles t in [32,64). Grid 2048 = 64 bh x 32 t.
// Block 64 threads: q = tid>>2 (16 rows), d0 = (tid&3)*16.
// ---------------------------------------------------------------------------
__global__ __launch_bounds__(64) void attn_combine(const unsigned short* __restrict__ Opart,
                                                   const float* __restrict__ Mpart,
                                                   const float* __restrict__ Lpart,
                                                   unsigned short* __restrict__ Ctx) {
    const int bid = blockIdx.x;
    const int bh  = bid >> 5;
    const int t   = 32 + (bid & 31);
    const int b   = bh >> 5;
    const int h   = bh & 31;
    const int tid = threadIdx.x;
    const int q   = tid >> 2;
    const int d0  = (tid & 3) << 4;

    const int p0 = bh * 64 + (t - 32) * 2;
    const int p1 = p0 + 1;
    float m1 = Mpart[p0 * 16 + q], m2 = Mpart[p1 * 16 + q];
    float l1 = Lpart[p0 * 16 + q], l2 = Lpart[p1 * 16 + q];
    float m  = fmaxf(m1, m2);
    float w1 = __expf(m1 - m), w2 = __expf(m2 - m);
    float rinv = 1.0f / (w1 * l1 + w2 * l2);

    const unsigned short* O1 = Opart + ((size_t)p0 * 16 + q) * 64 + d0;
    const unsigned short* O2 = Opart + ((size_t)p1 * 16 + q) * 64 + d0;
    unsigned short* dst =
        Ctx + (size_t)(b * S_ + 16 * t + q) * HID_ + h * HD_ + d0;

    short8 a0 = *(const short8*)&O1[0], a1 = *(const short8*)&O1[8];
    short8 b0 = *(const short8*)&O2[0], b1 = *(const short8*)&O2[8];
    short8 o0, o1;
#pragma unroll
    for (int i = 0; i < 8; ++i) {
        o0[i] = (short)f2bf((w1 * bf2f((unsigned short)a0[i]) +
                             w2 * bf2f((unsigned short)b0[i])) * rinv);
        o1[i] = (short)f2bf((w1 * bf2f((unsigned short)a1[i]) +
                             w2 * bf2f((unsigned short)b1[i])) * rinv);
    }
    *(short8*)&dst[0] = o0;
    *(short8*)&dst[8] = o1;
}

// ---------------------------------------------------------------------------
extern "C" void kernel_launch(void* const* d_in, const int* in_sizes, int n_in,
                              void* d_out, int out_size, void* d_ws, size_t ws_size,
                              hipStream_t stream) {
    const float* X    = (const float*)d_in[0];
    const float* cosT = (const float*)d_in[1];
    const float* sinT = (const float*)d_in[2];
    const float* Wq   = (const float*)d_in[3];
    const float* Wk   = (const float*)d_in[4];
    const float* Wv   = (const float*)d_in[5];
    const float* Wo   = (const float*)d_in[6];

    const int M = B_ * S_;          // 2048
    const size_t MB = 1024u * 1024u;

    // Workspace (28 MB), lifetime-aliased:
    //   [0,8):   Xbf -> Qbf      [8,10): Kbf   [10,12): Vt
    //   [12,20): Ctxbf           [20,28): WoT
    //   d_out (16 MB): QKVbf (12 MB, dead after convert_qkv); then attention
    //   partials Opart bf16 8 MB @0, Mpart/Lpart fp32 @8 MB; final GEMM then
    //   overwrites d_out with the fp32 result.
    char* ws = (char*)d_ws;
    unsigned short* Xbf   = (unsigned short*)(ws);
    unsigned short* Qbf   = (unsigned short*)(ws);
    unsigned short* WcatT = (unsigned short*)(ws + 8 * MB);
    unsigned short* Kbf   = (unsigned short*)(ws + 8 * MB);
    unsigned short* Vt    = (unsigned short*)(ws + 10 * MB);
    unsigned short* Ctxbf = (unsigned short*)(ws + 12 * MB);
    unsigned short* WoT   = (unsigned short*)(ws + 20 * MB);
    unsigned short* QKVbf = (unsigned short*)d_out;
    unsigned short* Opart = (unsigned short*)d_out;
    float* Mpart = (float*)((char*)d_out + 8 * MB);
    float* Lpart = (float*)((char*)d_out + 8 * MB + 512 * 1024);
    float* out = (float*)d_out;

    // X -> bf16
    convert_x<<<(M * HID_ / 4) / 256, 256, 0, stream>>>(X, Xbf);

    // All weight transposes (one kernel)
    transpose_all<<<10240, 256, 0, stream>>>(Wq, Wk, Wv, Wo, WcatT, WoT);

    // Fused QKV projection (bf16 MFMA) -> bf16 QKV in d_out scratch
    gemm_mfma<true><<<dim3(NQKV / 128, M / 128), 256, 0, stream>>>(
        Xbf, WcatT, QKVbf, M, NQKV, HID_);

    // Fused RoPE + layout conversion (one kernel)
    {
        int total = B_ * S_ * HQ_ * 32 + B_ * S_ * HKV_ * 32
                  + B_ * HKV_ * HD_ * (S_ / 4);
        convert_qkv<<<total / 256, 256, 0, stream>>>(QKVbf, cosT, sinT, Qbf, Kbf, Vt);
    }

    // Flash attention: single-wave blocks, software-pipelined, split-K 512
    attn_mfma<<<dim3(96, HQ_, B_), 64, 0, stream>>>(
        Qbf, Kbf, Vt, Ctxbf, Opart, Mpart, Lpart);

    // Merge split partials into Ctxbf (tiles 32..63)
    attn_combine<<<2048, 64, 0, stream>>>(Opart, Mpart, Lpart, Ctxbf);

    // Output projection (bf16 MFMA) -> fp32 out
    gemm_mfma<false><<<dim3(HID_ / 128, M / 128), 256, 0, stream>>>(
        Ctxbf, WoT, out, M, HID_, HID_);
}

// Round 7
// 263.001 us; speedup vs baseline: 7.7690x; 1.1971x over previous
//
#include <hip/hip_runtime.h>
#include <math.h>

#define B_   2
#define S_   1024
#define HID_ 2048
#define HQ_  32
#define HKV_ 8
#define HD_  64
#define NQKV 3072   // HID + 2*HKV*HD

using short8  = __attribute__((ext_vector_type(8))) short;
using floatx4 = __attribute__((ext_vector_type(4))) float;

__device__ __forceinline__ unsigned short f2bf(float x) {
    unsigned int u = __builtin_bit_cast(unsigned int, x);
    u += 0x7FFFu + ((u >> 16) & 1u);
    return (unsigned short)(u >> 16);
}
__device__ __forceinline__ float bf2f(unsigned short u) {
    return __builtin_bit_cast(float, (unsigned int)u << 16);
}

__device__ __forceinline__ void gl_lds16(const unsigned short* g, unsigned short* l) {
    __builtin_amdgcn_global_load_lds(
        (const __attribute__((address_space(1))) void*)g,
        (__attribute__((address_space(3))) void*)l, 16, 0, 0);
}

// ---------------------------------------------------------------------------
// bf16 MFMA GEMM (unchanged): C(MxN) = A(MxK) @ Bt(NxK)^T.
// ---------------------------------------------------------------------------
template <bool BF16OUT>
__global__ __launch_bounds__(256) void gemm_mfma(const unsigned short* __restrict__ A,
                                                 const unsigned short* __restrict__ Bt,
                                                 void* __restrict__ Cv,
                                                 int M, int N, int K) {
    __shared__ __align__(16) unsigned short As[128 * 32];
    __shared__ __align__(16) unsigned short Bs[128 * 32];

    const int tid  = threadIdx.x;
    const int w    = tid >> 6;
    const int lane = tid & 63;
    const int col  = lane & 15;
    const int quad = lane >> 4;
    const int m0 = blockIdx.y * 128;
    const int n0 = blockIdx.x * 128;
    const int wm = (w >> 1) * 64;
    const int wn = (w & 1) * 64;

    const int srow = lane >> 2;
    const int skof = (lane & 3) * 8;
    const unsigned short* Ag = A  + (size_t)(m0 + srow) * K + skof;
    const unsigned short* Bg = Bt + (size_t)(n0 + srow) * K + skof;
    const int rb = w * 16;

    floatx4 acc[4][4] = {};

    for (int k0 = 0; k0 < K; k0 += 32) {
        gl_lds16(Ag + (size_t)(rb     ) * K + k0, &As[(rb     ) * 32]);
        gl_lds16(Ag + (size_t)(rb + 64) * K + k0, &As[(rb + 64) * 32]);
        gl_lds16(Bg + (size_t)(rb     ) * K + k0, &Bs[(rb     ) * 32]);
        gl_lds16(Bg + (size_t)(rb + 64) * K + k0, &Bs[(rb + 64) * 32]);
        __syncthreads();

        short8 af[4], bfr[4];
#pragma unroll
        for (int i = 0; i < 4; ++i)
            af[i] = *(const short8*)&As[(wm + i * 16 + col) * 32 + quad * 8];
#pragma unroll
        for (int j = 0; j < 4; ++j)
            bfr[j] = *(const short8*)&Bs[(wn + j * 16 + col) * 32 + quad * 8];
#pragma unroll
        for (int i = 0; i < 4; ++i)
#pragma unroll
            for (int j = 0; j < 4; ++j)
                acc[i][j] = __builtin_amdgcn_mfma_f32_16x16x32_bf16(
                    af[i], bfr[j], acc[i][j], 0, 0, 0);
        __syncthreads();
    }

#pragma unroll
    for (int i = 0; i < 4; ++i)
#pragma unroll
        for (int j = 0; j < 4; ++j)
#pragma unroll
            for (int r = 0; r < 4; ++r) {
                size_t off = (size_t)(m0 + wm + i * 16 + quad * 4 + r) * N
                           + (n0 + wn + j * 16 + col);
                if constexpr (BF16OUT)
                    ((unsigned short*)Cv)[off] = f2bf(acc[i][j][r]);
                else
                    ((float*)Cv)[off] = acc[i][j][r];
            }
}

// ---------------------------------------------------------------------------
// fp32 -> bf16 elementwise (X)
// ---------------------------------------------------------------------------
__global__ __launch_bounds__(256) void convert_x(const float* __restrict__ in,
                                                 unsigned short* __restrict__ out) {
    int tid = blockIdx.x * 256 + threadIdx.x;
    float4 v = *(const float4*)&in[(size_t)tid * 4];
    ushort4 o = {f2bf(v.x), f2bf(v.y), f2bf(v.z), f2bf(v.w)};
    *(ushort4*)&out[(size_t)tid * 4] = o;
}

// ---------------------------------------------------------------------------
// All 4 weight transposes in ONE kernel (fp32 KxN -> bf16 NxK), 32x32 tiles.
// ---------------------------------------------------------------------------
__global__ __launch_bounds__(256) void transpose_all(const float* __restrict__ Wq,
                                                     const float* __restrict__ Wk,
                                                     const float* __restrict__ Wv,
                                                     const float* __restrict__ Wo,
                                                     unsigned short* __restrict__ WcatT,
                                                     unsigned short* __restrict__ WoT) {
    __shared__ float tile[32][33];
    int bid = blockIdx.x;
    const float* W;
    unsigned short* WT;
    int N, tn0, tk0;
    if (bid < 4096) {
        W = Wq; WT = WcatT; N = HID_;
        tn0 = (bid & 63) * 32; tk0 = (bid >> 6) * 32;
    } else if (bid < 5120) {
        bid -= 4096;
        W = Wk; WT = WcatT + (size_t)HID_ * HID_; N = 512;
        tn0 = (bid & 15) * 32; tk0 = (bid >> 4) * 32;
    } else if (bid < 6144) {
        bid -= 5120;
        W = Wv; WT = WcatT + (size_t)(HID_ + 512) * HID_; N = 512;
        tn0 = (bid & 15) * 32; tk0 = (bid >> 4) * 32;
    } else {
        bid -= 6144;
        W = Wo; WT = WoT; N = HID_;
        tn0 = (bid & 63) * 32; tk0 = (bid >> 6) * 32;
    }
    const int r  = threadIdx.x >> 3;
    const int c4 = (threadIdx.x & 7) * 4;
    float4 v = *(const float4*)&W[(size_t)(tk0 + r) * N + tn0 + c4];
    tile[r][c4 + 0] = v.x;
    tile[r][c4 + 1] = v.y;
    tile[r][c4 + 2] = v.z;
    tile[r][c4 + 3] = v.w;
    __syncthreads();
    ushort4 o = {f2bf(tile[c4 + 0][r]), f2bf(tile[c4 + 1][r]),
                 f2bf(tile[c4 + 2][r]), f2bf(tile[c4 + 3][r])};
    *(ushort4*)&WT[(size_t)(tn0 + r) * HID_ + tk0 + c4] = o;
}

// ---------------------------------------------------------------------------
// Fused RoPE + layout conversion, all three outputs in ONE kernel.
// ---------------------------------------------------------------------------
__global__ __launch_bounds__(256) void convert_qkv(const unsigned short* __restrict__ QKV,
                                                   const float* __restrict__ cosT,
                                                   const float* __restrict__ sinT,
                                                   unsigned short* __restrict__ Qbf,
                                                   unsigned short* __restrict__ Kbf,
                                                   unsigned short* __restrict__ Vt) {
    int tid = blockIdx.x * 256 + threadIdx.x;
    const int NQ = B_ * S_ * HQ_ * 32;
    const int NK = B_ * S_ * HKV_ * 32;
    if (tid < NQ) {
        int d = tid & 31;
        int h = (tid >> 5) & (HQ_ - 1);
        int s = (tid >> 10) & (S_ - 1);
        int b = tid >> 20;
        const unsigned short* row = QKV + (size_t)(b * S_ + s) * NQKV + h * HD_;
        float x0 = bf2f(row[d]), x1 = bf2f(row[d + 32]);
        float c0 = cosT[s * HD_ + d],      s0 = sinT[s * HD_ + d];
        float c1 = cosT[s * HD_ + d + 32], s1 = sinT[s * HD_ + d + 32];
        unsigned short* orow = Qbf + ((size_t)(b * HQ_ + h) * S_ + s) * HD_;
        orow[d]      = f2bf((x0 * c0 - x1 * s0) * 0.125f);
        orow[d + 32] = f2bf((x1 * c1 + x0 * s1) * 0.125f);
    } else if (tid < NQ + NK) {
        tid -= NQ;
        int d  = tid & 31;
        int kv = (tid >> 5) & (HKV_ - 1);
        int s  = (tid >> 8) & (S_ - 1);
        int b  = tid >> 18;
        const unsigned short* row = QKV + (size_t)(b * S_ + s) * NQKV + HID_ + kv * HD_;
        float x0 = bf2f(row[d]), x1 = bf2f(row[d + 32]);
        float c0 = cosT[s * HD_ + d],      s0 = sinT[s * HD_ + d];
        float c1 = cosT[s * HD_ + d + 32], s1 = sinT[s * HD_ + d + 32];
        unsigned short* orow = Kbf + ((size_t)(b * HKV_ + kv) * S_ + s) * HD_;
        orow[d]      = f2bf(x0 * c0 - x1 * s0);
        orow[d + 32] = f2bf(x1 * c1 + x0 * s1);
    } else {
        tid -= NQ + NK;
        int s4 = tid & 255;
        int d  = (tid >> 8) & (HD_ - 1);
        int kv = (tid >> 14) & (HKV_ - 1);
        int b  = tid >> 17;
        int s  = s4 * 4;
        const unsigned short* base =
            QKV + (size_t)b * S_ * NQKV + HID_ + 512 + kv * HD_ + d;
        ushort4 o;
        o.x = base[(size_t)(s + 0) * NQKV];
        o.y = base[(size_t)(s + 1) * NQKV];
        o.z = base[(size_t)(s + 2) * NQKV];
        o.w = base[(size_t)(s + 3) * NQKV];
        *(ushort4*)&Vt[((size_t)(b * HKV_ + kv) * HD_ + d) * S_ + s] = o;
    }
}

// ---------------------------------------------------------------------------
// Flash attention, GEMM-shaped (m97 skeleton): block = 256 threads = 4 waves.
// Block owns (b, kv-head, 16-q-row tile); wave w handles q-head 4*kv+w — the
// 4 heads SHARE the kv head, so K/V staged once in LDS serve all 4 waves, and
// all waves have the same causal range (block-uniform barriers, no idle).
// Per 64-key step: 4 global_load_lds per wave stage K (8 KB) + V^T (8 KB)
// into split 32-short planes (GEMM LDS geometry); frags via ds_read_b128;
// 16 MFMAs + online softmax (KQ^T orientation, per-lane m/l) per wave.
// Grid 64 x HKV x B = 1024 blocks, longest q-tiles first; 25 KB LDS ->
// all blocks resident in one generation (4 blocks = 16 waves per CU).
// ---------------------------------------------------------------------------
__global__ __launch_bounds__(256) void attn_mfma(const unsigned short* __restrict__ Qbf,
                                                 const unsigned short* __restrict__ Kbf,
                                                 const unsigned short* __restrict__ Vt,
                                                 unsigned short* __restrict__ Ctx) {
    const int t  = 63 - blockIdx.x;     // q-tile (16 rows), longest first
    const int kv = blockIdx.y;
    const int b  = blockIdx.z;
    const int w    = threadIdx.x >> 6;
    const int lane = threadIdx.x & 63;
    const int col  = lane & 15;
    const int quad = lane >> 4;

    const int h   = kv * 4 + w;
    const int bh  = b * HQ_ + h;
    const int bkv = b * HKV_ + kv;
    const int qw  = 16 * t;
    const int myq = qw + col;

    __shared__ __align__(16) unsigned short sK[2][64 * 32];  // [d-plane][key][32]
    __shared__ __align__(16) unsigned short sV[2][64 * 32];  // [k-plane][d][32]
    __shared__ __align__(16) unsigned short sP[4][16 * 72];  // per-wave P
    unsigned short* myP = sP[w];

    // Q B-fragments, held in registers for the whole kernel.
    const unsigned short* qrow = Qbf + ((size_t)bh * S_ + qw + col) * HD_;
    short8 bq0 = *(const short8*)&qrow[quad * 8];
    short8 bq1 = *(const short8*)&qrow[32 + quad * 8];

    const unsigned short* Kbase = Kbf + (size_t)bkv * S_ * HD_;
    const unsigned short* Vbase = Vt  + (size_t)bkv * HD_ * S_;

    // Staging geometry: wave w covers rows [16w,16w+16) of each plane.
    const int srow = 16 * w + (lane >> 2);   // K: key row / V: d row
    const int sch  = (lane & 3) * 8;         // shorts within the 32-plane
    unsigned short* dK0 = &sK[0][16 * w * 32];
    unsigned short* dK1 = &sK[1][16 * w * 32];
    unsigned short* dV0 = &sV[0][16 * w * 32];
    unsigned short* dV1 = &sV[1][16 * w * 32];

    floatx4 acc[4] = {};                // O[q][d]: row=q (quad*4+r), col=d
    float m_i = -1e30f, l_i = 0.f;
    const int nsteps = (16 * t + 79) >> 6;

    for (int it = 0; it < nsteps; ++it) {
        const int k0 = it * 64;
        // ---- stage K-tile and V^T-tile (shared by all 4 waves) ----
        gl_lds16(Kbase + (size_t)(k0 + srow) * HD_ + sch,      dK0);
        gl_lds16(Kbase + (size_t)(k0 + srow) * HD_ + 32 + sch, dK1);
        gl_lds16(Vbase + (size_t)srow * S_ + k0 + sch,         dV0);
        gl_lds16(Vbase + (size_t)srow * S_ + k0 + 32 + sch,    dV1);
        __syncthreads();

        // ---- S = K·Q^T: 4 tiles of 16 key-rows ----
        floatx4 sc[4];
#pragma unroll
        for (int tt = 0; tt < 4; ++tt) {
            short8 ak0 = *(const short8*)&sK[0][(16 * tt + col) * 32 + quad * 8];
            short8 ak1 = *(const short8*)&sK[1][(16 * tt + col) * 32 + quad * 8];
            floatx4 z = {0.f, 0.f, 0.f, 0.f};
            z = __builtin_amdgcn_mfma_f32_16x16x32_bf16(ak0, bq0, z, 0, 0, 0);
            z = __builtin_amdgcn_mfma_f32_16x16x32_bf16(ak1, bq1, z, 0, 0, 0);
            sc[tt] = z;
        }
        if (k0 + 63 > qw) {   // block-uniform: mask only the diagonal step
#pragma unroll
            for (int tt = 0; tt < 4; ++tt)
#pragma unroll
                for (int r = 0; r < 4; ++r)
                    if (k0 + 16 * tt + quad * 4 + r > myq) sc[tt][r] = -1e30f;
        }
        // ---- online softmax: 15 in-lane max + 2 shuffles ----
        float vmax = sc[0][0];
#pragma unroll
        for (int tt = 0; tt < 4; ++tt)
#pragma unroll
            for (int r = 0; r < 4; ++r)
                vmax = fmaxf(vmax, sc[tt][r]);
        vmax = fmaxf(vmax, __shfl_xor(vmax, 16, 64));
        vmax = fmaxf(vmax, __shfl_xor(vmax, 32, 64));
        const float mnew  = fmaxf(m_i, vmax);
        const float alpha = __expf(m_i - mnew);
        m_i = mnew;
        float lsum = 0.f;
#pragma unroll
        for (int tt = 0; tt < 4; ++tt) {
            float p0 = __expf(sc[tt][0] - mnew);
            float p1 = __expf(sc[tt][1] - mnew);
            float p2 = __expf(sc[tt][2] - mnew);
            float p3 = __expf(sc[tt][3] - mnew);
            lsum += (p0 + p1) + (p2 + p3);
            ushort4 pk = {f2bf(p0), f2bf(p1), f2bf(p2), f2bf(p3)};
            *(ushort4*)&myP[col * 72 + 16 * tt + quad * 4] = pk;
        }
        lsum += __shfl_xor(lsum, 16, 64);
        lsum += __shfl_xor(lsum, 32, 64);
        l_i = l_i * alpha + lsum;
        float a_r[4];
#pragma unroll
        for (int r = 0; r < 4; ++r)
            a_r[r] = __shfl(alpha, quad * 4 + r, 64);
#pragma unroll
        for (int nt = 0; nt < 4; ++nt)
#pragma unroll
            for (int r = 0; r < 4; ++r)
                acc[nt][r] *= a_r[r];
        // ---- PV: P (A-frag, via wave-private LDS) x V^T (B-frag, LDS) ----
        short8 pa0 = *(const short8*)&myP[col * 72 + quad * 8];
        short8 pa1 = *(const short8*)&myP[col * 72 + 32 + quad * 8];
#pragma unroll
        for (int nt = 0; nt < 4; ++nt) {
            short8 vb0 = *(const short8*)&sV[0][(nt * 16 + col) * 32 + quad * 8];
            short8 vb1 = *(const short8*)&sV[1][(nt * 16 + col) * 32 + quad * 8];
            acc[nt] = __builtin_amdgcn_mfma_f32_16x16x32_bf16(pa0, vb0, acc[nt], 0, 0, 0);
            acc[nt] = __builtin_amdgcn_mfma_f32_16x16x32_bf16(pa1, vb1, acc[nt], 0, 0, 0);
        }
        __syncthreads();
    }

    // ---- epilogue ----
    const float invl = 1.0f / l_i;
    float inv_r[4];
#pragma unroll
    for (int r = 0; r < 4; ++r)
        inv_r[r] = __shfl(invl, quad * 4 + r, 64);
#pragma unroll
    for (int nt = 0; nt < 4; ++nt)
#pragma unroll
        for (int r = 0; r < 4; ++r)
            Ctx[(size_t)(b * S_ + qw + quad * 4 + r) * HID_ + h * HD_ + nt * 16 + col] =
                f2bf(acc[nt][r] * inv_r[r]);
}

// ---------------------------------------------------------------------------
extern "C" void kernel_launch(void* const* d_in, const int* in_sizes, int n_in,
                              void* d_out, int out_size, void* d_ws, size_t ws_size,
                              hipStream_t stream) {
    const float* X    = (const float*)d_in[0];
    const float* cosT = (const float*)d_in[1];
    const float* sinT = (const float*)d_in[2];
    const float* Wq   = (const float*)d_in[3];
    const float* Wk   = (const float*)d_in[4];
    const float* Wv   = (const float*)d_in[5];
    const float* Wo   = (const float*)d_in[6];

    const int M = B_ * S_;          // 2048
    const size_t MB = 1024u * 1024u;

    // Workspace (28 MB), lifetime-aliased:
    //   [0,8):   Xbf -> Qbf      [8,10): Kbf   [10,12): Vt
    //   [12,20): Ctxbf           [20,28): WoT
    //   d_out (16 MB): QKVbf (12 MB, dead after convert_qkv); final GEMM then
    //   overwrites d_out with the fp32 result.
    char* ws = (char*)d_ws;
    unsigned short* Xbf   = (unsigned short*)(ws);
    unsigned short* Qbf   = (unsigned short*)(ws);
    unsigned short* WcatT = (unsigned short*)(ws + 8 * MB);
    unsigned short* Kbf   = (unsigned short*)(ws + 8 * MB);
    unsigned short* Vt    = (unsigned short*)(ws + 10 * MB);
    unsigned short* Ctxbf = (unsigned short*)(ws + 12 * MB);
    unsigned short* WoT   = (unsigned short*)(ws + 20 * MB);
    unsigned short* QKVbf = (unsigned short*)d_out;
    float* out = (float*)d_out;

    // X -> bf16
    convert_x<<<(M * HID_ / 4) / 256, 256, 0, stream>>>(X, Xbf);

    // All weight transposes (one kernel)
    transpose_all<<<10240, 256, 0, stream>>>(Wq, Wk, Wv, Wo, WcatT, WoT);

    // Fused QKV projection (bf16 MFMA) -> bf16 QKV in d_out scratch
    gemm_mfma<true><<<dim3(NQKV / 128, M / 128), 256, 0, stream>>>(
        Xbf, WcatT, QKVbf, M, NQKV, HID_);

    // Fused RoPE + layout conversion (one kernel)
    {
        int total = B_ * S_ * HQ_ * 32 + B_ * S_ * HKV_ * 32
                  + B_ * HKV_ * HD_ * (S_ / 4);
        convert_qkv<<<total / 256, 256, 0, stream>>>(QKVbf, cosT, sinT, Qbf, Kbf, Vt);
    }

    // Flash attention: GEMM-shaped blocks, LDS-shared K/V across the 4 heads
    // of each kv group.
    attn_mfma<<<dim3(64, HKV_, B_), 256, 0, stream>>>(Qbf, Kbf, Vt, Ctxbf);

    // Output projection (bf16 MFMA) -> fp32 out
    gemm_mfma<false><<<dim3(HID_ / 128, M / 128), 256, 0, stream>>>(
        Ctxbf, WoT, out, M, HID_, HID_);
}

// Round 8
// 245.566 us; speedup vs baseline: 8.3206x; 1.0710x over previous
//
#include <hip/hip_runtime.h>
#include <math.h>

#define B_   2
#define S_   1024
#define HID_ 2048
#define HQ_  32
#define HKV_ 8
#define HD_  64
#define NQKV 3072   // HID + 2*HKV*HD

using short8  = __attribute__((ext_vector_type(8))) short;
using floatx4 = __attribute__((ext_vector_type(4))) float;

__device__ __forceinline__ unsigned short f2bf(float x) {
    unsigned int u = __builtin_bit_cast(unsigned int, x);
    u += 0x7FFFu + ((u >> 16) & 1u);
    return (unsigned short)(u >> 16);
}
__device__ __forceinline__ float bf2f(unsigned short u) {
    return __builtin_bit_cast(float, (unsigned int)u << 16);
}

__device__ __forceinline__ void gl_lds16(const unsigned short* g, unsigned short* l) {
    __builtin_amdgcn_global_load_lds(
        (const __attribute__((address_space(1))) void*)g,
        (__attribute__((address_space(3))) void*)l, 16, 0, 0);
}

// ---------------------------------------------------------------------------
// QKV GEMM, SPLIT-K=2 (768 blocks = 3/CU). m97 skeleton: 128x128 tile, BK=32,
// 4 waves in 2x2 of 64x64. bid decode:
//   bid<512:  Q  (N in [0,2048)):  n=(bid&15)*128, m=((bid>>4)&15)*128, z=bid>>8
//   bid>=512: KV (N in [2048,3072)): b'=bid-512, n=2048+(b'&7)*128,
//             m=((b'>>3)&15)*128, z=b'>>7
// K chunk = [z*1024, z*1024+1024). Output: bf16 partials
//   Q:  Qp  + z*2048*2048  (row stride 2048)
//   KV: KVp + z*2048*1024  (row stride 1024, col = n-2048)
// ---------------------------------------------------------------------------
__global__ __launch_bounds__(256) void gemm_qkv(const unsigned short* __restrict__ A,
                                                const unsigned short* __restrict__ Bt,
                                                unsigned short* __restrict__ Qp,
                                                unsigned short* __restrict__ KVp) {
    __shared__ __align__(16) unsigned short As[128 * 32];
    __shared__ __align__(16) unsigned short Bs[128 * 32];

    int bid = blockIdx.x;
    int m0, n0, z, Nw, nc0;
    unsigned short* C;
    if (bid < 512) {
        n0 = (bid & 15) * 128; m0 = ((bid >> 4) & 15) * 128; z = bid >> 8;
        C = Qp + (size_t)z * 2048 * 2048; Nw = 2048; nc0 = n0;
    } else {
        bid -= 512;
        n0 = 2048 + (bid & 7) * 128; m0 = ((bid >> 3) & 15) * 128; z = bid >> 7;
        C = KVp + (size_t)z * 2048 * 1024; Nw = 1024; nc0 = n0 - 2048;
    }
    const int kbase = z * 1024;

    const int tid  = threadIdx.x;
    const int w    = tid >> 6;
    const int lane = tid & 63;
    const int col  = lane & 15;
    const int quad = lane >> 4;
    const int wm = (w >> 1) * 64;
    const int wn = (w & 1) * 64;

    const int srow = lane >> 2;
    const int skof = (lane & 3) * 8;
    const unsigned short* Ag = A  + (size_t)(m0 + srow) * HID_ + skof;
    const unsigned short* Bg = Bt + (size_t)(n0 + srow) * HID_ + skof;
    const int rb = w * 16;

    floatx4 acc[4][4] = {};

    for (int k0 = kbase; k0 < kbase + 1024; k0 += 32) {
        gl_lds16(Ag + (size_t)(rb     ) * HID_ + k0, &As[(rb     ) * 32]);
        gl_lds16(Ag + (size_t)(rb + 64) * HID_ + k0, &As[(rb + 64) * 32]);
        gl_lds16(Bg + (size_t)(rb     ) * HID_ + k0, &Bs[(rb     ) * 32]);
        gl_lds16(Bg + (size_t)(rb + 64) * HID_ + k0, &Bs[(rb + 64) * 32]);
        __syncthreads();

        short8 af[4], bfr[4];
#pragma unroll
        for (int i = 0; i < 4; ++i)
            af[i] = *(const short8*)&As[(wm + i * 16 + col) * 32 + quad * 8];
#pragma unroll
        for (int j = 0; j < 4; ++j)
            bfr[j] = *(const short8*)&Bs[(wn + j * 16 + col) * 32 + quad * 8];
#pragma unroll
        for (int i = 0; i < 4; ++i)
#pragma unroll
            for (int j = 0; j < 4; ++j)
                acc[i][j] = __builtin_amdgcn_mfma_f32_16x16x32_bf16(
                    af[i], bfr[j], acc[i][j], 0, 0, 0);
        __syncthreads();
    }

#pragma unroll
    for (int i = 0; i < 4; ++i)
#pragma unroll
        for (int j = 0; j < 4; ++j)
#pragma unroll
            for (int r = 0; r < 4; ++r)
                C[(size_t)(m0 + wm + i * 16 + quad * 4 + r) * Nw
                  + (nc0 + wn + j * 16 + col)] = f2bf(acc[i][j][r]);
}

// ---------------------------------------------------------------------------
// Wo GEMM, SPLIT-K=2 (512 blocks). z=0 -> fp32 direct to out; z=1 -> bf16 p1.
// ---------------------------------------------------------------------------
__global__ __launch_bounds__(256) void gemm_wo(const unsigned short* __restrict__ A,
                                               const unsigned short* __restrict__ Bt,
                                               float* __restrict__ Cf,
                                               unsigned short* __restrict__ Cp1) {
    __shared__ __align__(16) unsigned short As[128 * 32];
    __shared__ __align__(16) unsigned short Bs[128 * 32];

    const int m0 = blockIdx.y * 128;
    const int n0 = blockIdx.x * 128;
    const int z  = blockIdx.z;
    const int kbase = z * 1024;

    const int tid  = threadIdx.x;
    const int w    = tid >> 6;
    const int lane = tid & 63;
    const int col  = lane & 15;
    const int quad = lane >> 4;
    const int wm = (w >> 1) * 64;
    const int wn = (w & 1) * 64;

    const int srow = lane >> 2;
    const int skof = (lane & 3) * 8;
    const unsigned short* Ag = A  + (size_t)(m0 + srow) * HID_ + skof;
    const unsigned short* Bg = Bt + (size_t)(n0 + srow) * HID_ + skof;
    const int rb = w * 16;

    floatx4 acc[4][4] = {};

    for (int k0 = kbase; k0 < kbase + 1024; k0 += 32) {
        gl_lds16(Ag + (size_t)(rb     ) * HID_ + k0, &As[(rb     ) * 32]);
        gl_lds16(Ag + (size_t)(rb + 64) * HID_ + k0, &As[(rb + 64) * 32]);
        gl_lds16(Bg + (size_t)(rb     ) * HID_ + k0, &Bs[(rb     ) * 32]);
        gl_lds16(Bg + (size_t)(rb + 64) * HID_ + k0, &Bs[(rb + 64) * 32]);
        __syncthreads();

        short8 af[4], bfr[4];
#pragma unroll
        for (int i = 0; i < 4; ++i)
            af[i] = *(const short8*)&As[(wm + i * 16 + col) * 32 + quad * 8];
#pragma unroll
        for (int j = 0; j < 4; ++j)
            bfr[j] = *(const short8*)&Bs[(wn + j * 16 + col) * 32 + quad * 8];
#pragma unroll
        for (int i = 0; i < 4; ++i)
#pragma unroll
            for (int j = 0; j < 4; ++j)
                acc[i][j] = __builtin_amdgcn_mfma_f32_16x16x32_bf16(
                    af[i], bfr[j], acc[i][j], 0, 0, 0);
        __syncthreads();
    }

#pragma unroll
    for (int i = 0; i < 4; ++i)
#pragma unroll
        for (int j = 0; j < 4; ++j)
#pragma unroll
            for (int r = 0; r < 4; ++r) {
                size_t off = (size_t)(m0 + wm + i * 16 + quad * 4 + r) * HID_
                           + (n0 + wn + j * 16 + col);
                if (z == 0) Cf[off] = acc[i][j][r];
                else        Cp1[off] = f2bf(acc[i][j][r]);
            }
}

// out[i] += bf2f(p1[i]), vectorized (4 per thread). 4096 blocks x 256.
__global__ __launch_bounds__(256) void reduce_wo(float* __restrict__ out,
                                                 const unsigned short* __restrict__ p1) {
    int i4 = (blockIdx.x * 256 + threadIdx.x) * 4;
    float4 o = *(float4*)&out[i4];
    ushort4 p = *(const ushort4*)&p1[i4];
    o.x += bf2f(p.x); o.y += bf2f(p.y); o.z += bf2f(p.z); o.w += bf2f(p.w);
    *(float4*)&out[i4] = o;
}

// ---------------------------------------------------------------------------
// fp32 -> bf16 elementwise (X)
// ---------------------------------------------------------------------------
__global__ __launch_bounds__(256) void convert_x(const float* __restrict__ in,
                                                 unsigned short* __restrict__ out) {
    int tid = blockIdx.x * 256 + threadIdx.x;
    float4 v = *(const float4*)&in[(size_t)tid * 4];
    ushort4 o = {f2bf(v.x), f2bf(v.y), f2bf(v.z), f2bf(v.w)};
    *(ushort4*)&out[(size_t)tid * 4] = o;
}

// ---------------------------------------------------------------------------
// Weight transposes (fp32 KxN -> bf16 NxK), 32x32 LDS tiles.
// transpose_qkv: Wq|Wk|Wv -> WcatT (6144 blocks); transpose_wo: Wo -> WoT.
// ---------------------------------------------------------------------------
__global__ __launch_bounds__(256) void transpose_qkv(const float* __restrict__ Wq,
                                                     const float* __restrict__ Wk,
                                                     const float* __restrict__ Wv,
                                                     unsigned short* __restrict__ WcatT) {
    __shared__ float tile[32][33];
    int bid = blockIdx.x;
    const float* W;
    unsigned short* WT;
    int N, tn0, tk0;
    if (bid < 4096) {
        W = Wq; WT = WcatT; N = HID_;
        tn0 = (bid & 63) * 32; tk0 = (bid >> 6) * 32;
    } else if (bid < 5120) {
        bid -= 4096;
        W = Wk; WT = WcatT + (size_t)HID_ * HID_; N = 512;
        tn0 = (bid & 15) * 32; tk0 = (bid >> 4) * 32;
    } else {
        bid -= 5120;
        W = Wv; WT = WcatT + (size_t)(HID_ + 512) * HID_; N = 512;
        tn0 = (bid & 15) * 32; tk0 = (bid >> 4) * 32;
    }
    const int r  = threadIdx.x >> 3;
    const int c4 = (threadIdx.x & 7) * 4;
    float4 v = *(const float4*)&W[(size_t)(tk0 + r) * N + tn0 + c4];
    tile[r][c4 + 0] = v.x;
    tile[r][c4 + 1] = v.y;
    tile[r][c4 + 2] = v.z;
    tile[r][c4 + 3] = v.w;
    __syncthreads();
    ushort4 o = {f2bf(tile[c4 + 0][r]), f2bf(tile[c4 + 1][r]),
                 f2bf(tile[c4 + 2][r]), f2bf(tile[c4 + 3][r])};
    *(ushort4*)&WT[(size_t)(tn0 + r) * HID_ + tk0 + c4] = o;
}

__global__ __launch_bounds__(256) void transpose_wo(const float* __restrict__ Wo,
                                                    unsigned short* __restrict__ WoT) {
    __shared__ float tile[32][33];
    int bid = blockIdx.x;
    const int tn0 = (bid & 63) * 32;
    const int tk0 = (bid >> 6) * 32;
    const int r  = threadIdx.x >> 3;
    const int c4 = (threadIdx.x & 7) * 4;
    float4 v = *(const float4*)&Wo[(size_t)(tk0 + r) * HID_ + tn0 + c4];
    tile[r][c4 + 0] = v.x;
    tile[r][c4 + 1] = v.y;
    tile[r][c4 + 2] = v.z;
    tile[r][c4 + 3] = v.w;
    __syncthreads();
    ushort4 o = {f2bf(tile[c4 + 0][r]), f2bf(tile[c4 + 1][r]),
                 f2bf(tile[c4 + 2][r]), f2bf(tile[c4 + 3][r])};
    *(ushort4*)&WoT[(size_t)(tn0 + r) * HID_ + tk0 + c4] = o;
}

// ---------------------------------------------------------------------------
// Fused split-K reduce + RoPE + layout conversion.
// Q from Qp (2 bf16 partials, row stride 2048); K/V from KVp (2 partials,
// row stride 1024; K at col kv*64+d, V at col 512+kv*64+d).
// ---------------------------------------------------------------------------
__global__ __launch_bounds__(256) void convert_qkv(const unsigned short* __restrict__ Qp,
                                                   const unsigned short* __restrict__ KVp,
                                                   const float* __restrict__ cosT,
                                                   const float* __restrict__ sinT,
                                                   unsigned short* __restrict__ Qbf,
                                                   unsigned short* __restrict__ Kbf,
                                                   unsigned short* __restrict__ Vt) {
    const size_t QSTR  = (size_t)2048 * 2048;   // Q partial stride (elems)
    const size_t KVSTR = (size_t)2048 * 1024;   // KV partial stride
    int tid = blockIdx.x * 256 + threadIdx.x;
    const int NQ = B_ * S_ * HQ_ * 32;
    const int NK = B_ * S_ * HKV_ * 32;
    if (tid < NQ) {
        int d = tid & 31;
        int h = (tid >> 5) & (HQ_ - 1);
        int s = (tid >> 10) & (S_ - 1);
        int b = tid >> 20;
        const unsigned short* row = Qp + (size_t)(b * S_ + s) * 2048 + h * HD_;
        float x0 = bf2f(row[d])      + bf2f(row[QSTR + d]);
        float x1 = bf2f(row[d + 32]) + bf2f(row[QSTR + d + 32]);
        float c0 = cosT[s * HD_ + d],      s0 = sinT[s * HD_ + d];
        float c1 = cosT[s * HD_ + d + 32], s1 = sinT[s * HD_ + d + 32];
        unsigned short* orow = Qbf + ((size_t)(b * HQ_ + h) * S_ + s) * HD_;
        orow[d]      = f2bf((x0 * c0 - x1 * s0) * 0.125f);
        orow[d + 32] = f2bf((x1 * c1 + x0 * s1) * 0.125f);
    } else if (tid < NQ + NK) {
        tid -= NQ;
        int d  = tid & 31;
        int kv = (tid >> 5) & (HKV_ - 1);
        int s  = (tid >> 8) & (S_ - 1);
        int b  = tid >> 18;
        const unsigned short* row = KVp + (size_t)(b * S_ + s) * 1024 + kv * HD_;
        float x0 = bf2f(row[d])      + bf2f(row[KVSTR + d]);
        float x1 = bf2f(row[d + 32]) + bf2f(row[KVSTR + d + 32]);
        float c0 = cosT[s * HD_ + d],      s0 = sinT[s * HD_ + d];
        float c1 = cosT[s * HD_ + d + 32], s1 = sinT[s * HD_ + d + 32];
        unsigned short* orow = Kbf + ((size_t)(b * HKV_ + kv) * S_ + s) * HD_;
        orow[d]      = f2bf(x0 * c0 - x1 * s0);
        orow[d + 32] = f2bf(x1 * c1 + x0 * s1);
    } else {
        tid -= NQ + NK;
        int s4 = tid & 255;
        int d  = (tid >> 8) & (HD_ - 1);
        int kv = (tid >> 14) & (HKV_ - 1);
        int b  = tid >> 17;
        int s  = s4 * 4;
        const unsigned short* base =
            KVp + ((size_t)(b * S_ + s)) * 1024 + 512 + kv * HD_ + d;
        ushort4 o;
#pragma unroll
        for (int j = 0; j < 4; ++j) {
            float v = bf2f(base[(size_t)j * 1024]) +
                      bf2f(base[KVSTR + (size_t)j * 1024]);
            ((unsigned short*)&o)[j] = f2bf(v);
        }
        *(ushort4*)&Vt[((size_t)(b * HKV_ + kv) * HD_ + d) * S_ + s] = o;
    }
}

// ---------------------------------------------------------------------------
// Flash attention, GEMM-shaped (unchanged from round 7): block = 4 waves =
// 4 q-heads sharing one kv head; K/V staged once in LDS per 64-key step.
// ---------------------------------------------------------------------------
__global__ __launch_bounds__(256) void attn_mfma(const unsigned short* __restrict__ Qbf,
                                                 const unsigned short* __restrict__ Kbf,
                                                 const unsigned short* __restrict__ Vt,
                                                 unsigned short* __restrict__ Ctx) {
    const int t  = 63 - blockIdx.x;
    const int kv = blockIdx.y;
    const int b  = blockIdx.z;
    const int w    = threadIdx.x >> 6;
    const int lane = threadIdx.x & 63;
    const int col  = lane & 15;
    const int quad = lane >> 4;

    const int h   = kv * 4 + w;
    const int bh  = b * HQ_ + h;
    const int bkv = b * HKV_ + kv;
    const int qw  = 16 * t;
    const int myq = qw + col;

    __shared__ __align__(16) unsigned short sK[2][64 * 32];
    __shared__ __align__(16) unsigned short sV[2][64 * 32];
    __shared__ __align__(16) unsigned short sP[4][16 * 72];
    unsigned short* myP = sP[w];

    const unsigned short* qrow = Qbf + ((size_t)bh * S_ + qw + col) * HD_;
    short8 bq0 = *(const short8*)&qrow[quad * 8];
    short8 bq1 = *(const short8*)&qrow[32 + quad * 8];

    const unsigned short* Kbase = Kbf + (size_t)bkv * S_ * HD_;
    const unsigned short* Vbase = Vt  + (size_t)bkv * HD_ * S_;

    const int srow = 16 * w + (lane >> 2);
    const int sch  = (lane & 3) * 8;
    unsigned short* dK0 = &sK[0][16 * w * 32];
    unsigned short* dK1 = &sK[1][16 * w * 32];
    unsigned short* dV0 = &sV[0][16 * w * 32];
    unsigned short* dV1 = &sV[1][16 * w * 32];

    floatx4 acc[4] = {};
    float m_i = -1e30f, l_i = 0.f;
    const int nsteps = (16 * t + 79) >> 6;

    for (int it = 0; it < nsteps; ++it) {
        const int k0 = it * 64;
        gl_lds16(Kbase + (size_t)(k0 + srow) * HD_ + sch,      dK0);
        gl_lds16(Kbase + (size_t)(k0 + srow) * HD_ + 32 + sch, dK1);
        gl_lds16(Vbase + (size_t)srow * S_ + k0 + sch,         dV0);
        gl_lds16(Vbase + (size_t)srow * S_ + k0 + 32 + sch,    dV1);
        __syncthreads();

        floatx4 sc[4];
#pragma unroll
        for (int tt = 0; tt < 4; ++tt) {
            short8 ak0 = *(const short8*)&sK[0][(16 * tt + col) * 32 + quad * 8];
            short8 ak1 = *(const short8*)&sK[1][(16 * tt + col) * 32 + quad * 8];
            floatx4 z = {0.f, 0.f, 0.f, 0.f};
            z = __builtin_amdgcn_mfma_f32_16x16x32_bf16(ak0, bq0, z, 0, 0, 0);
            z = __builtin_amdgcn_mfma_f32_16x16x32_bf16(ak1, bq1, z, 0, 0, 0);
            sc[tt] = z;
        }
        if (k0 + 63 > qw) {
#pragma unroll
            for (int tt = 0; tt < 4; ++tt)
#pragma unroll
                for (int r = 0; r < 4; ++r)
                    if (k0 + 16 * tt + quad * 4 + r > myq) sc[tt][r] = -1e30f;
        }
        float vmax = sc[0][0];
#pragma unroll
        for (int tt = 0; tt < 4; ++tt)
#pragma unroll
            for (int r = 0; r < 4; ++r)
                vmax = fmaxf(vmax, sc[tt][r]);
        vmax = fmaxf(vmax, __shfl_xor(vmax, 16, 64));
        vmax = fmaxf(vmax, __shfl_xor(vmax, 32, 64));
        const float mnew  = fmaxf(m_i, vmax);
        const float alpha = __expf(m_i - mnew);
        m_i = mnew;
        float lsum = 0.f;
#pragma unroll
        for (int tt = 0; tt < 4; ++tt) {
            float p0 = __expf(sc[tt][0] - mnew);
            float p1 = __expf(sc[tt][1] - mnew);
            float p2 = __expf(sc[tt][2] - mnew);
            float p3 = __expf(sc[tt][3] - mnew);
            lsum += (p0 + p1) + (p2 + p3);
            ushort4 pk = {f2bf(p0), f2bf(p1), f2bf(p2), f2bf(p3)};
            *(ushort4*)&myP[col * 72 + 16 * tt + quad * 4] = pk;
        }
        lsum += __shfl_xor(lsum, 16, 64);
        lsum += __shfl_xor(lsum, 32, 64);
        l_i = l_i * alpha + lsum;
        float a_r[4];
#pragma unroll
        for (int r = 0; r < 4; ++r)
            a_r[r] = __shfl(alpha, quad * 4 + r, 64);
#pragma unroll
        for (int nt = 0; nt < 4; ++nt)
#pragma unroll
            for (int r = 0; r < 4; ++r)
                acc[nt][r] *= a_r[r];
        short8 pa0 = *(const short8*)&myP[col * 72 + quad * 8];
        short8 pa1 = *(const short8*)&myP[col * 72 + 32 + quad * 8];
#pragma unroll
        for (int nt = 0; nt < 4; ++nt) {
            short8 vb0 = *(const short8*)&sV[0][(nt * 16 + col) * 32 + quad * 8];
            short8 vb1 = *(const short8*)&sV[1][(nt * 16 + col) * 32 + quad * 8];
            acc[nt] = __builtin_amdgcn_mfma_f32_16x16x32_bf16(pa0, vb0, acc[nt], 0, 0, 0);
            acc[nt] = __builtin_amdgcn_mfma_f32_16x16x32_bf16(pa1, vb1, acc[nt], 0, 0, 0);
        }
        __syncthreads();
    }

    const float invl = 1.0f / l_i;
    float inv_r[4];
#pragma unroll
    for (int r = 0; r < 4; ++r)
        inv_r[r] = __shfl(invl, quad * 4 + r, 64);
#pragma unroll
    for (int nt = 0; nt < 4; ++nt)
#pragma unroll
        for (int r = 0; r < 4; ++r)
            Ctx[(size_t)(b * S_ + qw + quad * 4 + r) * HID_ + h * HD_ + nt * 16 + col] =
                f2bf(acc[nt][r] * inv_r[r]);
}

// ---------------------------------------------------------------------------
extern "C" void kernel_launch(void* const* d_in, const int* in_sizes, int n_in,
                              void* d_out, int out_size, void* d_ws, size_t ws_size,
                              hipStream_t stream) {
    const float* X    = (const float*)d_in[0];
    const float* cosT = (const float*)d_in[1];
    const float* sinT = (const float*)d_in[2];
    const float* Wq   = (const float*)d_in[3];
    const float* Wk   = (const float*)d_in[4];
    const float* Wv   = (const float*)d_in[5];
    const float* Wo   = (const float*)d_in[6];

    const int M = B_ * S_;          // 2048
    const size_t MB = 1024u * 1024u;

    // Memory schedule (ws 28 MiB, d_out 16 MiB), lifetime-aliased:
    //  1 convert_x:     Xbf -> ws[0,8)
    //  2 transpose_qkv: WcatT -> ws[8,20)
    //  3 gemm_qkv:      Q partials (2x8 MiB bf16) -> d_out; KV partials
    //                   (2x4 MiB bf16) -> ws[20,28)
    //  4 convert_qkv:   reduce+RoPE -> Qbf ws[0,8), Kbf ws[8,10), Vt ws[10,12)
    //  5 transpose_wo:  WoT -> ws[12,20)
    //  6 attn:          Ctxbf -> ws[20,28)
    //  7 gemm_wo:       z=0 fp32 -> d_out; z=1 bf16 p1 -> ws[0,8)
    //  8 reduce_wo:     d_out += p1 (in place)
    char* ws = (char*)d_ws;
    unsigned short* Xbf   = (unsigned short*)(ws);
    unsigned short* Qbf   = (unsigned short*)(ws);
    unsigned short* WcatT = (unsigned short*)(ws + 8 * MB);
    unsigned short* Kbf   = (unsigned short*)(ws + 8 * MB);
    unsigned short* Vt    = (unsigned short*)(ws + 10 * MB);
    unsigned short* WoT   = (unsigned short*)(ws + 12 * MB);
    unsigned short* KVp   = (unsigned short*)(ws + 20 * MB);
    unsigned short* Ctxbf = (unsigned short*)(ws + 20 * MB);
    unsigned short* Wop1  = (unsigned short*)(ws);
    unsigned short* Qp    = (unsigned short*)d_out;
    float* out = (float*)d_out;

    // 1. X -> bf16
    convert_x<<<(M * HID_ / 4) / 256, 256, 0, stream>>>(X, Xbf);

    // 2. Wq|Wk|Wv -> WcatT
    transpose_qkv<<<6144, 256, 0, stream>>>(Wq, Wk, Wv, WcatT);

    // 3. QKV projection, split-K=2 (768 blocks)
    gemm_qkv<<<768, 256, 0, stream>>>(Xbf, WcatT, Qp, KVp);

    // 4. Fused split-K reduce + RoPE + layout conversion
    {
        int total = B_ * S_ * HQ_ * 32 + B_ * S_ * HKV_ * 32
                  + B_ * HKV_ * HD_ * (S_ / 4);
        convert_qkv<<<total / 256, 256, 0, stream>>>(Qp, KVp, cosT, sinT,
                                                     Qbf, Kbf, Vt);
    }

    // 5. Wo -> WoT
    transpose_wo<<<4096, 256, 0, stream>>>(Wo, WoT);

    // 6. Flash attention
    attn_mfma<<<dim3(64, HKV_, B_), 256, 0, stream>>>(Qbf, Kbf, Vt, Ctxbf);

    // 7. Output projection, split-K=2 (512 blocks)
    gemm_wo<<<dim3(16, 16, 2), 256, 0, stream>>>(Ctxbf, WoT, out, Wop1);

    // 8. out += p1
    reduce_wo<<<(M * HID_ / 4) / 256, 256, 0, stream>>>(out, Wop1);
}